// Round 1
// 1645.433 us; speedup vs baseline: 1.2384x; 1.2384x over previous
//
#include <hip/hip_runtime.h>

#define NN 100000

typedef __attribute__((ext_vector_type(8))) __bf16 bf16x8;
typedef __attribute__((ext_vector_type(8))) unsigned short ushort8v;
typedef __attribute__((ext_vector_type(4))) float f32x4;

__device__ __forceinline__ float bf2f(unsigned short u) {
    union { unsigned int ui; float f; } c;
    c.ui = ((unsigned int)u) << 16;
    return c.f;
}

__device__ __forceinline__ unsigned short f2bf(float f) {
    union { float ff; unsigned int ui; } c;
    c.ff = f;
    unsigned int u = c.ui;
    u += 0x7FFFu + ((u >> 16) & 1u);   // round-to-nearest-even
    return (unsigned short)(u >> 16);
}

// truncation split: x = hi + resid, hi = bf16-truncate(x)
__device__ __forceinline__ unsigned short trunc_hi(float x, float& resid) {
    union { float f; unsigned int u; } c, h;
    c.f = x;
    h.u = c.u & 0xFFFF0000u;
    resid = x - h.f;
    return (unsigned short)(c.u >> 16);
}

__device__ __forceinline__ unsigned short trunc_bits(float x) {
    union { float f; unsigned int u; } c;
    c.f = x;
    return (unsigned short)(c.u >> 16);
}

__global__ void MultiTaskGCN_37623913513359_kernel() {}

// flags[0]: edge index format, 1 = int64, 0 = int32
// flags[1]: float dtype, 1 = bf16-backed, 0 = fp32-backed
__global__ void probe_fmt(const int* ei, const unsigned short* x, int* flags) {
    if (blockIdx.x != 0 || threadIdx.x != 0) return;
    int any = 0;
    for (int i = 0; i < 64; ++i) any |= ei[2 * i + 1];
    flags[0] = (any == 0) ? 1 : 0;
    int bf = 1;
    for (int i = 0; i < 512; ++i) {
        float v = bf2f(x[2 * i]);
        float av = v < 0.0f ? -v : v;
        if (!(v == v) || av > 1.0e6f) { bf = 0; break; }
    }
    flags[1] = bf;
}

__device__ __forceinline__ int edge_src(const int* ei, int is64, int e) {
    if (is64) return ei[2 * e];
    return ei[e];
}
__device__ __forceinline__ int edge_dst(const int* ei, int is64, int e, int E) {
    if (is64) return ei[2 * (E + e)];
    return ei[E + e];
}

__device__ __forceinline__ float load_f(const void* p, int dt, size_t i) {
    if (dt) return bf2f(((const unsigned short*)p)[i]);
    return ((const float*)p)[i];
}

__global__ __launch_bounds__(256) void count_deg_i(const int* ei, const int* flags,
                                                   int* degi, int E) {
    int t = blockIdx.x * 256 + threadIdx.x;
    if (t >= E) return;
    int is64 = flags[0];
    int s = edge_src(ei, is64, t);
    int d = edge_dst(ei, is64, t, E);
    if (((unsigned)s) >= NN || ((unsigned)d) >= NN) return;
    atomicAdd(&degi[d], 1);
}

__global__ __launch_bounds__(256) void make_dinv(const int* degi, float* dinv) {
    int i = blockIdx.x * 256 + threadIdx.x;
    if (i < NN) dinv[i] = rsqrtf((float)degi[i] + 1.0f);   // +1 self loop
}

// single-block exclusive scan of degi -> rowptr (NN+1 entries)
__global__ __launch_bounds__(1024) void scan_rowptr(const int* degi, int* rowptr) {
    __shared__ int part[1024];
    int tid = threadIdx.x;
    const int chunk = (NN + 1023) / 1024;   // 98
    int base = tid * chunk;
    int s = 0;
    for (int j = 0; j < chunk; ++j) {
        int i = base + j;
        if (i < NN) s += degi[i];
    }
    part[tid] = s;
    __syncthreads();
    for (int off = 1; off < 1024; off <<= 1) {
        int v = (tid >= off) ? part[tid - off] : 0;
        __syncthreads();
        part[tid] += v;
        __syncthreads();
    }
    int run = (tid == 0) ? 0 : part[tid - 1];
    for (int j = 0; j < chunk; ++j) {
        int i = base + j;
        if (i < NN) {
            rowptr[i] = run;
            run += degi[i];
        }
    }
    if (tid == 1023) rowptr[NN] = part[1023];
}

// fill CSR: packed entry = (w_bits << 32) | src
__global__ __launch_bounds__(256) void fill_csr(const int* ei, const int* flags,
                                                const float* dinv, const int* rowptr,
                                                int* cursor, unsigned long long* csr,
                                                int E) {
    int t = blockIdx.x * 256 + threadIdx.x;
    if (t >= E) return;
    int is64 = flags[0];
    int s = edge_src(ei, is64, t);
    int d = edge_dst(ei, is64, t, E);
    if (((unsigned)s) >= NN || ((unsigned)d) >= NN) return;
    int pos = rowptr[d] + atomicAdd(&cursor[d], 1);
    float w = dinv[s] * dinv[d];
    union { float ff; unsigned int ui; } c;
    c.ff = w;
    csr[pos] = ((unsigned long long)c.ui << 32) | (unsigned int)s;
}

// W1 (row-major [512][256], fp32 or bf16) -> W1T hi/lo bf16 [256 n][512 k]
__global__ __launch_bounds__(256) void prep_w1t(const void* W1, const int* flags,
                                                unsigned short* hi, unsigned short* lo) {
    int t = blockIdx.x * 256 + threadIdx.x;
    if (t >= 256 * 512) return;
    int n = t >> 9, k = t & 511;
    float v = load_f(W1, flags[1], (size_t)k * 256 + n);
    float r;
    hi[t] = trunc_hi(v, r);
    lo[t] = trunc_bits(r);
}

// [Wc | Wk | Wd | 0] -> WcatT hi/lo bf16 [64 n][256 k]
__global__ __launch_bounds__(256) void prep_wcat(const void* Wc, const void* Wk,
                                                 const void* Wd, const int* flags,
                                                 unsigned short* hi, unsigned short* lo) {
    int t = blockIdx.x * 256 + threadIdx.x;
    if (t >= 64 * 256) return;
    int n = t >> 8, k = t & 255;
    int dt = flags[1];
    float v = 0.0f;
    if (n < 40) v = load_f(Wc, dt, (size_t)k * 40 + n);
    else if (n < 56) v = load_f(Wk, dt, (size_t)k * 16 + (n - 40));
    else if (n == 56) v = load_f(Wd, dt, k);
    float r;
    hi[t] = trunc_hi(v, r);
    lo[t] = trunc_bits(r);
}

// ---------------- MFMA GEMM ----------------
// C[M,N] (bf16) = A[M,K] @ B[K,N], with B pre-transposed+split as BT_hi/BT_lo [N][K] bf16.
// A is split on the fly (fp32 path) or used as-is (bf16 path).
// Split product: A_hi*B_hi + A_hi*B_lo + A_lo*B_hi  (A_lo*B_lo ~2^-16, dropped)

template<int NB>
struct StageRegs {
    ushort8v ah[2], al[2], bh[NB], bl[NB];
};

template<int NB>
__device__ __forceinline__ StageRegs<NB> stage_load(const void* A, const unsigned short* BTh,
                                                    const unsigned short* BTl, int M, int K,
                                                    int m0, int n0, int k0,
                                                    int lane, int wid, int adt, bool blo) {
    StageRegs<NB> s;
#pragma unroll
    for (int half = 0; half < 2; ++half) {
        int gr = m0 + lane + half * 64;
        if (gr >= M) gr = M - 1;
        if (adt == 0) {
            const float* ap = (const float*)A + (size_t)gr * K + k0 + wid * 8;
            f32x4 v0 = *(const f32x4*)ap;
            f32x4 v1 = *(const f32x4*)(ap + 4);
            ushort8v h, l;
#pragma unroll
            for (int j = 0; j < 4; ++j) {
                float r;
                h[j] = trunc_hi(v0[j], r);
                l[j] = trunc_bits(r);
            }
#pragma unroll
            for (int j = 0; j < 4; ++j) {
                float r;
                h[4 + j] = trunc_hi(v1[j], r);
                l[4 + j] = trunc_bits(r);
            }
            s.ah[half] = h;
            s.al[half] = l;
        } else {
            s.ah[half] = *(const ushort8v*)((const unsigned short*)A + (size_t)gr * K + k0 + wid * 8);
        }
    }
#pragma unroll
    for (int nb = 0; nb < NB; ++nb) {
        size_t o = (size_t)(n0 + lane + nb * 64) * K + k0 + wid * 8;
        s.bh[nb] = *(const ushort8v*)(BTh + o);
        if (blo) s.bl[nb] = *(const ushort8v*)(BTl + o);
    }
    return s;
}

template<int BM, int BN, int NB>
__device__ __forceinline__ void stage_write(ushort8v (&As)[2][4][BM], ushort8v (&Bs)[2][4][BN],
                                            const StageRegs<NB>& s, int lane, int wid,
                                            bool alo, bool blo) {
    // kg = wid, row = lane: each wave writes a contiguous 1KB run -> conflict-free
    As[0][wid][lane] = s.ah[0];
    As[0][wid][lane + 64] = s.ah[1];
    if (alo) {
        As[1][wid][lane] = s.al[0];
        As[1][wid][lane + 64] = s.al[1];
    }
#pragma unroll
    for (int nb = 0; nb < NB; ++nb) {
        Bs[0][wid][lane + nb * 64] = s.bh[nb];
        if (blo) Bs[1][wid][lane + nb * 64] = s.bl[nb];
    }
}

template<int BM, int BN, int NF>
__device__ __forceinline__ void mfma_step(const ushort8v (&As)[2][4][BM],
                                          const ushort8v (&Bs)[2][4][BN],
                                          f32x4 (&acc)[4][NF],
                                          int wm, int wn, int lane, bool alo, bool blo) {
    const int lr = lane & 15;
    const int lk = lane >> 4;     // k-group 0..3, k = lk*8 + e
    bf16x8 ah[4], al[4];
#pragma unroll
    for (int i = 0; i < 4; ++i) {
        ah[i] = *(const bf16x8*)&As[0][lk][wm * 64 + i * 16 + lr];
        if (alo) al[i] = *(const bf16x8*)&As[1][lk][wm * 64 + i * 16 + lr];
    }
    bf16x8 bh[NF], bl[NF];
#pragma unroll
    for (int j = 0; j < NF; ++j) {
        bh[j] = *(const bf16x8*)&Bs[0][lk][wn * (BN / 2) + j * 16 + lr];
        if (blo) bl[j] = *(const bf16x8*)&Bs[1][lk][wn * (BN / 2) + j * 16 + lr];
    }
#pragma unroll
    for (int i = 0; i < 4; ++i) {
#pragma unroll
        for (int j = 0; j < NF; ++j) {
            acc[i][j] = __builtin_amdgcn_mfma_f32_16x16x32_bf16(ah[i], bh[j], acc[i][j], 0, 0, 0);
            if (blo) acc[i][j] = __builtin_amdgcn_mfma_f32_16x16x32_bf16(ah[i], bl[j], acc[i][j], 0, 0, 0);
            if (alo) acc[i][j] = __builtin_amdgcn_mfma_f32_16x16x32_bf16(al[i], bh[j], acc[i][j], 0, 0, 0);
        }
    }
}

// amode: 0 = A follows flags[1] (fp32 -> split, bf16 -> as-is), 2 = A is raw bf16 (our buffer)
template<int BN, int NF>
__global__ __launch_bounds__(256) void gemm_mfma(const void* A, const unsigned short* BTh,
                                                 const unsigned short* BTl, unsigned short* C,
                                                 int M, int N, int K, const int* flags, int amode) {
    constexpr int BM = 128;
    constexpr int NB = BN / 64;
    __shared__ ushort8v As[2][4][BM];   // [hi/lo][kg][row], 16 KB
    __shared__ ushort8v Bs[2][4][BN];   // [hi/lo][kg][col]

    const int tid = threadIdx.x;
    const int lane = tid & 63;
    const int wid = tid >> 6;
    const int wm = wid >> 1;            // 2x2 wave grid, wave tile 64 x (NF*16)
    const int wn = wid & 1;
    const int dt = flags[1];
    const int adt = (amode == 0) ? dt : 1;
    const bool alo = (adt == 0);
    const bool blo = (dt == 0);
    const int m0 = blockIdx.x * BM;
    const int n0 = blockIdx.y * BN;

    f32x4 zero = {0.0f, 0.0f, 0.0f, 0.0f};
    f32x4 acc[4][NF];
#pragma unroll
    for (int i = 0; i < 4; ++i)
#pragma unroll
        for (int j = 0; j < NF; ++j) acc[i][j] = zero;

    StageRegs<NB> sA = stage_load<NB>(A, BTh, BTl, M, K, m0, n0, 0, lane, wid, adt, blo);
    const int nT = K >> 5;              // K-steps of 32; always even here (16 or 8)
    for (int t = 0; t < nT; t += 2) {
        __syncthreads();
        stage_write<BM, BN, NB>(As, Bs, sA, lane, wid, alo, blo);
        __syncthreads();
        StageRegs<NB> sB = stage_load<NB>(A, BTh, BTl, M, K, m0, n0, (t + 1) << 5, lane, wid, adt, blo);
        mfma_step<BM, BN, NF>(As, Bs, acc, wm, wn, lane, alo, blo);
        __syncthreads();
        stage_write<BM, BN, NB>(As, Bs, sB, lane, wid, alo, blo);
        __syncthreads();
        if (t + 2 < nT)
            sA = stage_load<NB>(A, BTh, BTl, M, K, m0, n0, (t + 2) << 5, lane, wid, adt, blo);
        mfma_step<BM, BN, NF>(As, Bs, acc, wm, wn, lane, alo, blo);
    }

    // C/D layout (m89-verified): col = lane&15, row = (lane>>4)*4 + reg
    const int lr = lane & 15;
    const int lq = lane >> 4;
#pragma unroll
    for (int i = 0; i < 4; ++i) {
#pragma unroll
        for (int rr = 0; rr < 4; ++rr) {
            int row = m0 + wm * 64 + i * 16 + lq * 4 + rr;
            if (row < M) {
#pragma unroll
                for (int j = 0; j < NF; ++j) {
                    int col = n0 + wn * (BN / 2) + j * 16 + lr;
                    C[(size_t)row * N + col] = f2bf(acc[i][j][rr]);
                }
            }
        }
    }
}

// layer-1 aggregation by pull + fused epilogue: one wave per destination node.
__global__ __launch_bounds__(256) void gather_h(const int* rowptr,
                                                const unsigned long long* csr,
                                                const unsigned short* xwb,
                                                const void* b1,
                                                const float* dinv,
                                                const int* flags,
                                                unsigned short* hb) {
    int node = (blockIdx.x * 256 + threadIdx.x) >> 6;
    int lane = threadIdx.x & 63;
    if (node >= NN) return;
    int beg = rowptr[node], end = rowptr[node + 1];
    float a0 = 0.f, a1 = 0.f, a2 = 0.f, a3 = 0.f;
    for (int e = beg; e < end; ++e) {
        unsigned long long p = csr[e];
        int s = (int)(unsigned int)(p & 0xFFFFFFFFu);
        union { unsigned int ui; float ff; } c;
        c.ui = (unsigned int)(p >> 32);
        float w = c.ff;
        unsigned long long v = *(const unsigned long long*)(xwb + (size_t)s * 256 + lane * 4);
        a0 += w * bf2f((unsigned short)v);
        a1 += w * bf2f((unsigned short)(v >> 16));
        a2 += w * bf2f((unsigned short)(v >> 32));
        a3 += w * bf2f((unsigned short)(v >> 48));
    }
    int dt = flags[1];
    float di = dinv[node];
    float sl = di * di;
    size_t base = (size_t)node * 256 + lane * 4;
    unsigned long long v = *(const unsigned long long*)(xwb + base);
    float r0 = sl * bf2f((unsigned short)v)         + a0 + load_f(b1, dt, lane * 4 + 0);
    float r1 = sl * bf2f((unsigned short)(v >> 16)) + a1 + load_f(b1, dt, lane * 4 + 1);
    float r2 = sl * bf2f((unsigned short)(v >> 32)) + a2 + load_f(b1, dt, lane * 4 + 2);
    float r3 = sl * bf2f((unsigned short)(v >> 48)) + a3 + load_f(b1, dt, lane * 4 + 3);
    if (r0 < 0.f) r0 = 0.f;
    if (r1 < 0.f) r1 = 0.f;
    if (r2 < 0.f) r2 = 0.f;
    if (r3 < 0.f) r3 = 0.f;
    unsigned long long o = (unsigned long long)f2bf(r0)
                         | ((unsigned long long)f2bf(r1) << 16)
                         | ((unsigned long long)f2bf(r2) << 32)
                         | ((unsigned long long)f2bf(r3) << 48);
    *(unsigned long long*)(hb + base) = o;
}

// layer-2 aggregation by pull + fused head routing: one wave per node, lane = col
__global__ __launch_bounds__(256) void gather_out(const int* rowptr,
                                                  const unsigned long long* csr,
                                                  const unsigned short* hw2b,
                                                  const void* bc, const void* bk,
                                                  const void* bd,
                                                  const float* dinv,
                                                  const int* flags,
                                                  void* outv) {
    int node = (blockIdx.x * 256 + threadIdx.x) >> 6;
    int lane = threadIdx.x & 63;
    if (node >= NN) return;
    int beg = rowptr[node], end = rowptr[node + 1];
    float acc = 0.f;
    for (int e = beg; e < end; ++e) {
        unsigned long long p = csr[e];
        int s = (int)(unsigned int)(p & 0xFFFFFFFFu);
        union { unsigned int ui; float ff; } c;
        c.ui = (unsigned int)(p >> 32);
        acc += c.ff * bf2f(hw2b[(size_t)s * 64 + lane]);
    }
    if (lane >= 57) return;
    int dt = flags[1];
    float di = dinv[node];
    float v = di * di * bf2f(hw2b[(size_t)node * 64 + lane]) + acc;
    size_t o;
    if (lane < 40) {
        v += load_f(bc, dt, lane);
        o = (size_t)node * 40 + lane;
    } else if (lane < 56) {
        v += load_f(bk, dt, lane - 40);
        o = (size_t)NN * 40 + (size_t)node * 16 + (lane - 40);
    } else {
        v += load_f(bd, dt, 0);
        o = (size_t)NN * 56 + node;
    }
    if (dt) ((unsigned short*)outv)[o] = f2bf(v);
    else ((float*)outv)[o] = v;
}

extern "C" void kernel_launch(void* const* d_in, const int* in_sizes, int n_in,
                              void* d_out, int out_size, void* d_ws, size_t ws_size,
                              hipStream_t stream) {
    const void* x  = d_in[0];
    const int* ei  = (const int*)d_in[1];
    const void* W1 = d_in[2];
    const void* b1 = d_in[3];
    const void* Wc = d_in[4];
    const void* bc = d_in[5];
    const void* Wk = d_in[6];
    const void* bk = d_in[7];
    const void* Wd = d_in[8];
    const void* bd = d_in[9];

    int E = in_sizes[1] / 2;

    hipError_t herr = hipSuccess;
    hipError_t e;

    // workspace layout (256B-aligned offsets)
    char* ws = (char*)d_ws;
    size_t off = 0;
    int* flags = (int*)(ws + off);                      off += 256;
    float* dinv = (float*)(ws + off);                   off += 400128;
    int* rowptr = (int*)(ws + off);                     off += 400384;   // NN+1
    char* scr = ws + off;                               off += 800256;
    // scratch phase 1 (graph build): degi + cursor
    int* degi = (int*)scr;
    int* cursor = (int*)(scr + 400128);
    // scratch phase 2 (after fill_csr, degi/cursor dead): split weight tables
    unsigned short* w1t_hi = (unsigned short*)scr;                  // 256*512*2 = 262144
    unsigned short* w1t_lo = (unsigned short*)(scr + 262144);       // 262144
    unsigned short* wct_hi = (unsigned short*)(scr + 524288);       // 64*256*2 = 32768
    unsigned short* wct_lo = (unsigned short*)(scr + 557056);       // 32768 (total 589824 <= 800256)
    unsigned long long* csr = (unsigned long long*)(ws + off); off += (size_t)E * 8;
    unsigned short* xwb = (unsigned short*)(ws + off);  off += (size_t)NN * 256 * 2;
    unsigned short* hb = (unsigned short*)(ws + off);   off += (size_t)NN * 256 * 2;
    unsigned short* hw2b = (unsigned short*)(ws + off); off += (size_t)NN * 64 * 2;

    int ws_bad = (off > ws_size) ? 1 : 0;

    if (!ws_bad) {
        e = hipMemsetAsync(degi, 0, (size_t)NN * 4, stream);
        if (herr == hipSuccess && e != hipSuccess) herr = e;
        e = hipMemsetAsync(cursor, 0, (size_t)NN * 4, stream);
        if (herr == hipSuccess && e != hipSuccess) herr = e;

        probe_fmt<<<1, 64, 0, stream>>>(ei, (const unsigned short*)x, flags);
        count_deg_i<<<(E + 255) / 256, 256, 0, stream>>>(ei, flags, degi, E);
        make_dinv<<<(NN + 255) / 256, 256, 0, stream>>>(degi, dinv);
        scan_rowptr<<<1, 1024, 0, stream>>>(degi, rowptr);
        fill_csr<<<(E + 255) / 256, 256, 0, stream>>>(ei, flags, dinv, rowptr,
                                                      cursor, csr, E);

        // degi/cursor dead from here; build transposed split-bf16 weight tables
        prep_w1t<<<512, 256, 0, stream>>>(W1, flags, w1t_hi, w1t_lo);
        prep_wcat<<<64, 256, 0, stream>>>(Wc, Wk, Wd, flags, wct_hi, wct_lo);

        // layer 1: xw = x @ W1   (M=100000, K=512, N=256), MFMA split-bf16
        {
            dim3 grid((NN + 127) / 128, 2);
            gemm_mfma<128, 4><<<grid, 256, 0, stream>>>(x, w1t_hi, w1t_lo, xwb,
                                                        NN, 256, 512, flags, 0);
        }
        gather_h<<<(NN + 3) / 4, 256, 0, stream>>>(rowptr, csr, xwb, b1, dinv,
                                                   flags, hb);

        // layer 2: hw2 = h @ Wcat   (M=100000, K=256, N=64), A already bf16
        {
            dim3 grid((NN + 127) / 128, 1);
            gemm_mfma<64, 2><<<grid, 256, 0, stream>>>(hb, wct_hi, wct_lo, hw2b,
                                                       NN, 64, 256, flags, 2);
        }
        gather_out<<<(NN + 3) / 4, 256, 0, stream>>>(rowptr, csr, hw2b, bc, bk, bd,
                                                     dinv, flags, d_out);
    }

    e = hipGetLastError();
    if (herr == hipSuccess && e != hipSuccess) herr = e;

    if (herr != hipSuccess) {
        (void)hipMemsetAsync(d_out, 0x41 + ((int)herr & 7), 128, stream);
    }
    if (ws_bad) {
        (void)hipMemsetAsync(d_out, 0x58, 128, stream);
    }
}

// Round 2
// 1345.575 us; speedup vs baseline: 1.5144x; 1.2228x over previous
//
#include <hip/hip_runtime.h>

#define NN 100000

typedef __attribute__((ext_vector_type(8))) __bf16 bf16x8;
typedef __attribute__((ext_vector_type(8))) unsigned short ushort8v;
typedef __attribute__((ext_vector_type(4))) float f32x4;

__device__ __forceinline__ float bf2f(unsigned short u) {
    union { unsigned int ui; float f; } c;
    c.ui = ((unsigned int)u) << 16;
    return c.f;
}

__device__ __forceinline__ unsigned short f2bf(float f) {
    union { float ff; unsigned int ui; } c;
    c.ff = f;
    unsigned int u = c.ui;
    u += 0x7FFFu + ((u >> 16) & 1u);   // round-to-nearest-even
    return (unsigned short)(u >> 16);
}

// truncation split: x = hi + resid, hi = bf16-truncate(x)
__device__ __forceinline__ unsigned short trunc_hi(float x, float& resid) {
    union { float f; unsigned int u; } c, h;
    c.f = x;
    h.u = c.u & 0xFFFF0000u;
    resid = x - h.f;
    return (unsigned short)(c.u >> 16);
}

__device__ __forceinline__ unsigned short trunc_bits(float x) {
    union { float f; unsigned int u; } c;
    c.f = x;
    return (unsigned short)(c.u >> 16);
}

__global__ void MultiTaskGCN_37623913513359_kernel() {}

// flags[0]: edge index format, 1 = int64, 0 = int32
// flags[1]: float dtype, 1 = bf16-backed, 0 = fp32-backed
__global__ void probe_fmt(const int* ei, const unsigned short* x, int* flags) {
    if (blockIdx.x != 0 || threadIdx.x != 0) return;
    int any = 0;
    for (int i = 0; i < 64; ++i) any |= ei[2 * i + 1];
    flags[0] = (any == 0) ? 1 : 0;
    int bf = 1;
    for (int i = 0; i < 512; ++i) {
        float v = bf2f(x[2 * i]);
        float av = v < 0.0f ? -v : v;
        if (!(v == v) || av > 1.0e6f) { bf = 0; break; }
    }
    flags[1] = bf;
}

__device__ __forceinline__ int edge_src(const int* ei, int is64, int e) {
    if (is64) return ei[2 * e];
    return ei[e];
}
__device__ __forceinline__ int edge_dst(const int* ei, int is64, int e, int E) {
    if (is64) return ei[2 * (E + e)];
    return ei[E + e];
}

__device__ __forceinline__ float load_f(const void* p, int dt, size_t i) {
    if (dt) return bf2f(((const unsigned short*)p)[i]);
    return ((const float*)p)[i];
}

__global__ __launch_bounds__(256) void count_deg_i(const int* ei, const int* flags,
                                                   int* degi, int E) {
    int t = blockIdx.x * 256 + threadIdx.x;
    if (t >= E) return;
    int is64 = flags[0];
    int s = edge_src(ei, is64, t);
    int d = edge_dst(ei, is64, t, E);
    if (((unsigned)s) >= NN || ((unsigned)d) >= NN) return;
    atomicAdd(&degi[d], 1);
}

__global__ __launch_bounds__(256) void make_dinv(const int* degi, float* dinv) {
    int i = blockIdx.x * 256 + threadIdx.x;
    if (i < NN) dinv[i] = rsqrtf((float)degi[i] + 1.0f);   // +1 self loop
}

// single-block exclusive scan of degi -> rowptr (NN+1 entries)
__global__ __launch_bounds__(1024) void scan_rowptr(const int* degi, int* rowptr) {
    __shared__ int part[1024];
    int tid = threadIdx.x;
    const int chunk = (NN + 1023) / 1024;   // 98
    int base = tid * chunk;
    int s = 0;
    for (int j = 0; j < chunk; ++j) {
        int i = base + j;
        if (i < NN) s += degi[i];
    }
    part[tid] = s;
    __syncthreads();
    for (int off = 1; off < 1024; off <<= 1) {
        int v = (tid >= off) ? part[tid - off] : 0;
        __syncthreads();
        part[tid] += v;
        __syncthreads();
    }
    int run = (tid == 0) ? 0 : part[tid - 1];
    for (int j = 0; j < chunk; ++j) {
        int i = base + j;
        if (i < NN) {
            rowptr[i] = run;
            run += degi[i];
        }
    }
    if (tid == 1023) rowptr[NN] = part[1023];
}

// fill CSR: packed entry = (w_bits << 32) | src
__global__ __launch_bounds__(256) void fill_csr(const int* ei, const int* flags,
                                                const float* dinv, const int* rowptr,
                                                int* cursor, unsigned long long* csr,
                                                int E) {
    int t = blockIdx.x * 256 + threadIdx.x;
    if (t >= E) return;
    int is64 = flags[0];
    int s = edge_src(ei, is64, t);
    int d = edge_dst(ei, is64, t, E);
    if (((unsigned)s) >= NN || ((unsigned)d) >= NN) return;
    int pos = rowptr[d] + atomicAdd(&cursor[d], 1);
    float w = dinv[s] * dinv[d];
    union { float ff; unsigned int ui; } c;
    c.ff = w;
    csr[pos] = ((unsigned long long)c.ui << 32) | (unsigned int)s;
}

// W1 (row-major [512][256], fp32 or bf16) -> W1T hi/lo bf16 [256 n][512 k]
__global__ __launch_bounds__(256) void prep_w1t(const void* W1, const int* flags,
                                                unsigned short* hi, unsigned short* lo) {
    int t = blockIdx.x * 256 + threadIdx.x;
    if (t >= 256 * 512) return;
    int n = t >> 9, k = t & 511;
    float v = load_f(W1, flags[1], (size_t)k * 256 + n);
    float r;
    hi[t] = trunc_hi(v, r);
    lo[t] = trunc_bits(r);
}

// [Wc | Wk | Wd | 0] -> WcatT hi/lo bf16 [64 n][256 k]
__global__ __launch_bounds__(256) void prep_wcat(const void* Wc, const void* Wk,
                                                 const void* Wd, const int* flags,
                                                 unsigned short* hi, unsigned short* lo) {
    int t = blockIdx.x * 256 + threadIdx.x;
    if (t >= 64 * 256) return;
    int n = t >> 8, k = t & 255;
    int dt = flags[1];
    float v = 0.0f;
    if (n < 40) v = load_f(Wc, dt, (size_t)k * 40 + n);
    else if (n < 56) v = load_f(Wk, dt, (size_t)k * 16 + (n - 40));
    else if (n == 56) v = load_f(Wd, dt, k);
    float r;
    hi[t] = trunc_hi(v, r);
    lo[t] = trunc_bits(r);
}

// ---------------- MFMA GEMM ----------------
// C[M,N] (bf16) = A[M,K] @ B[K,N], with B pre-transposed+split as BT_hi/BT_lo [N][K] bf16.
// A is split on the fly (fp32 path) or used as-is (bf16 path).
// Split product: A_hi*B_hi + A_hi*B_lo + A_lo*B_hi  (A_lo*B_lo ~2^-16, dropped)

template<int NB>
struct StageRegs {
    ushort8v ah[2], al[2], bh[NB], bl[NB];
};

template<int NB>
__device__ __forceinline__ StageRegs<NB> stage_load(const void* A, const unsigned short* BTh,
                                                    const unsigned short* BTl, int M, int K,
                                                    int m0, int n0, int k0,
                                                    int lane, int wid, int adt, bool blo) {
    StageRegs<NB> s;
#pragma unroll
    for (int half = 0; half < 2; ++half) {
        int gr = m0 + lane + half * 64;
        if (gr >= M) gr = M - 1;
        if (adt == 0) {
            const float* ap = (const float*)A + (size_t)gr * K + k0 + wid * 8;
            f32x4 v0 = *(const f32x4*)ap;
            f32x4 v1 = *(const f32x4*)(ap + 4);
            ushort8v h, l;
#pragma unroll
            for (int j = 0; j < 4; ++j) {
                float r;
                h[j] = trunc_hi(v0[j], r);
                l[j] = trunc_bits(r);
            }
#pragma unroll
            for (int j = 0; j < 4; ++j) {
                float r;
                h[4 + j] = trunc_hi(v1[j], r);
                l[4 + j] = trunc_bits(r);
            }
            s.ah[half] = h;
            s.al[half] = l;
        } else {
            s.ah[half] = *(const ushort8v*)((const unsigned short*)A + (size_t)gr * K + k0 + wid * 8);
        }
    }
#pragma unroll
    for (int nb = 0; nb < NB; ++nb) {
        size_t o = (size_t)(n0 + lane + nb * 64) * K + k0 + wid * 8;
        s.bh[nb] = *(const ushort8v*)(BTh + o);
        if (blo) s.bl[nb] = *(const ushort8v*)(BTl + o);
    }
    return s;
}

template<int BM, int BN, int NB>
__device__ __forceinline__ void stage_write(ushort8v (&As)[2][4][BM], ushort8v (&Bs)[2][4][BN],
                                            const StageRegs<NB>& s, int lane, int wid,
                                            bool alo, bool blo) {
    // kg = wid, row = lane: each wave writes a contiguous 1KB run -> conflict-free
    As[0][wid][lane] = s.ah[0];
    As[0][wid][lane + 64] = s.ah[1];
    if (alo) {
        As[1][wid][lane] = s.al[0];
        As[1][wid][lane + 64] = s.al[1];
    }
#pragma unroll
    for (int nb = 0; nb < NB; ++nb) {
        Bs[0][wid][lane + nb * 64] = s.bh[nb];
        if (blo) Bs[1][wid][lane + nb * 64] = s.bl[nb];
    }
}

template<int BM, int BN, int NF>
__device__ __forceinline__ void mfma_step(const ushort8v (&As)[2][4][BM],
                                          const ushort8v (&Bs)[2][4][BN],
                                          f32x4 (&acc)[4][NF],
                                          int wm, int wn, int lane, bool alo, bool blo) {
    const int lr = lane & 15;
    const int lk = lane >> 4;     // k-group 0..3, k = lk*8 + e
    bf16x8 ah[4], al[4];
#pragma unroll
    for (int i = 0; i < 4; ++i) {
        ah[i] = *(const bf16x8*)&As[0][lk][wm * 64 + i * 16 + lr];
        if (alo) al[i] = *(const bf16x8*)&As[1][lk][wm * 64 + i * 16 + lr];
    }
    bf16x8 bh[NF], bl[NF];
#pragma unroll
    for (int j = 0; j < NF; ++j) {
        bh[j] = *(const bf16x8*)&Bs[0][lk][wn * (BN / 2) + j * 16 + lr];
        if (blo) bl[j] = *(const bf16x8*)&Bs[1][lk][wn * (BN / 2) + j * 16 + lr];
    }
#pragma unroll
    for (int i = 0; i < 4; ++i) {
#pragma unroll
        for (int j = 0; j < NF; ++j) {
            acc[i][j] = __builtin_amdgcn_mfma_f32_16x16x32_bf16(ah[i], bh[j], acc[i][j], 0, 0, 0);
            if (blo) acc[i][j] = __builtin_amdgcn_mfma_f32_16x16x32_bf16(ah[i], bl[j], acc[i][j], 0, 0, 0);
            if (alo) acc[i][j] = __builtin_amdgcn_mfma_f32_16x16x32_bf16(al[i], bh[j], acc[i][j], 0, 0, 0);
        }
    }
}

// amode: 0 = A follows flags[1] (fp32 -> split, bf16 -> as-is), 2 = A is raw bf16 (our buffer)
template<int BN, int NF>
__global__ __launch_bounds__(256) void gemm_mfma(const void* A, const unsigned short* BTh,
                                                 const unsigned short* BTl, unsigned short* C,
                                                 int M, int N, int K, const int* flags, int amode) {
    constexpr int BM = 128;
    constexpr int NB = BN / 64;
    __shared__ ushort8v As[2][4][BM];   // [hi/lo][kg][row], 16 KB
    __shared__ ushort8v Bs[2][4][BN];   // [hi/lo][kg][col]

    const int tid = threadIdx.x;
    const int lane = tid & 63;
    const int wid = tid >> 6;
    const int wm = wid >> 1;            // 2x2 wave grid, wave tile 64 x (NF*16)
    const int wn = wid & 1;
    const int dt = flags[1];
    const int adt = (amode == 0) ? dt : 1;
    const bool alo = (adt == 0);
    const bool blo = (dt == 0);
    const int m0 = blockIdx.x * BM;
    const int n0 = blockIdx.y * BN;

    f32x4 zero = {0.0f, 0.0f, 0.0f, 0.0f};
    f32x4 acc[4][NF];
#pragma unroll
    for (int i = 0; i < 4; ++i)
#pragma unroll
        for (int j = 0; j < NF; ++j) acc[i][j] = zero;

    StageRegs<NB> sA = stage_load<NB>(A, BTh, BTl, M, K, m0, n0, 0, lane, wid, adt, blo);
    const int nT = K >> 5;              // K-steps of 32; always even here (16 or 8)
    for (int t = 0; t < nT; t += 2) {
        __syncthreads();
        stage_write<BM, BN, NB>(As, Bs, sA, lane, wid, alo, blo);
        __syncthreads();
        StageRegs<NB> sB = stage_load<NB>(A, BTh, BTl, M, K, m0, n0, (t + 1) << 5, lane, wid, adt, blo);
        mfma_step<BM, BN, NF>(As, Bs, acc, wm, wn, lane, alo, blo);
        __syncthreads();
        stage_write<BM, BN, NB>(As, Bs, sB, lane, wid, alo, blo);
        __syncthreads();
        if (t + 2 < nT)
            sA = stage_load<NB>(A, BTh, BTl, M, K, m0, n0, (t + 2) << 5, lane, wid, adt, blo);
        mfma_step<BM, BN, NF>(As, Bs, acc, wm, wn, lane, alo, blo);
    }

    // C/D layout (m89-verified): col = lane&15, row = (lane>>4)*4 + reg
    const int lr = lane & 15;
    const int lq = lane >> 4;
#pragma unroll
    for (int i = 0; i < 4; ++i) {
#pragma unroll
        for (int rr = 0; rr < 4; ++rr) {
            int row = m0 + wm * 64 + i * 16 + lq * 4 + rr;
            if (row < M) {
#pragma unroll
                for (int j = 0; j < NF; ++j) {
                    int col = n0 + wn * (BN / 2) + j * 16 + lr;
                    C[(size_t)row * N + col] = f2bf(acc[i][j][rr]);
                }
            }
        }
    }
}

// layer-1 aggregation by pull + fused epilogue: one wave per destination node.
// 4-deep unrolled edge loop: 4 independent accumulator chains keep 4 random
// 512B row-gathers in flight per wave (MLP; was 1 with the rolled loop).
__global__ __launch_bounds__(256) void gather_h(const int* rowptr,
                                                const unsigned long long* csr,
                                                const unsigned short* xwb,
                                                const void* b1,
                                                const float* dinv,
                                                const int* flags,
                                                unsigned short* hb) {
    int node = (blockIdx.x * 256 + threadIdx.x) >> 6;
    int lane = threadIdx.x & 63;
    if (node >= NN) return;
    int beg = rowptr[node], end = rowptr[node + 1];
    const unsigned short* xp = xwb + (size_t)lane * 4;

    float a0[4] = {0.f, 0.f, 0.f, 0.f};
    float a1[4] = {0.f, 0.f, 0.f, 0.f};
    float a2[4] = {0.f, 0.f, 0.f, 0.f};
    float a3[4] = {0.f, 0.f, 0.f, 0.f};

    int e = beg;
    for (; e + 4 <= end; e += 4) {
        unsigned long long p0 = csr[e + 0];
        unsigned long long p1 = csr[e + 1];
        unsigned long long p2 = csr[e + 2];
        unsigned long long p3 = csr[e + 3];
        unsigned long long v0 = *(const unsigned long long*)(xp + ((size_t)(unsigned int)p0) * 256);
        unsigned long long v1 = *(const unsigned long long*)(xp + ((size_t)(unsigned int)p1) * 256);
        unsigned long long v2 = *(const unsigned long long*)(xp + ((size_t)(unsigned int)p2) * 256);
        unsigned long long v3 = *(const unsigned long long*)(xp + ((size_t)(unsigned int)p3) * 256);
        union { unsigned int ui; float ff; } w0, w1, w2, w3;
        w0.ui = (unsigned int)(p0 >> 32);
        w1.ui = (unsigned int)(p1 >> 32);
        w2.ui = (unsigned int)(p2 >> 32);
        w3.ui = (unsigned int)(p3 >> 32);
        a0[0] += w0.ff * bf2f((unsigned short)v0);
        a0[1] += w0.ff * bf2f((unsigned short)(v0 >> 16));
        a0[2] += w0.ff * bf2f((unsigned short)(v0 >> 32));
        a0[3] += w0.ff * bf2f((unsigned short)(v0 >> 48));
        a1[0] += w1.ff * bf2f((unsigned short)v1);
        a1[1] += w1.ff * bf2f((unsigned short)(v1 >> 16));
        a1[2] += w1.ff * bf2f((unsigned short)(v1 >> 32));
        a1[3] += w1.ff * bf2f((unsigned short)(v1 >> 48));
        a2[0] += w2.ff * bf2f((unsigned short)v2);
        a2[1] += w2.ff * bf2f((unsigned short)(v2 >> 16));
        a2[2] += w2.ff * bf2f((unsigned short)(v2 >> 32));
        a2[3] += w2.ff * bf2f((unsigned short)(v2 >> 48));
        a3[0] += w3.ff * bf2f((unsigned short)v3);
        a3[1] += w3.ff * bf2f((unsigned short)(v3 >> 16));
        a3[2] += w3.ff * bf2f((unsigned short)(v3 >> 32));
        a3[3] += w3.ff * bf2f((unsigned short)(v3 >> 48));
    }
    for (; e < end; ++e) {
        unsigned long long p = csr[e];
        union { unsigned int ui; float ff; } c;
        c.ui = (unsigned int)(p >> 32);
        unsigned long long v = *(const unsigned long long*)(xp + ((size_t)(unsigned int)p) * 256);
        a0[0] += c.ff * bf2f((unsigned short)v);
        a0[1] += c.ff * bf2f((unsigned short)(v >> 16));
        a0[2] += c.ff * bf2f((unsigned short)(v >> 32));
        a0[3] += c.ff * bf2f((unsigned short)(v >> 48));
    }

    int dt = flags[1];
    float di = dinv[node];
    float sl = di * di;
    size_t base = (size_t)node * 256 + lane * 4;
    unsigned long long v = *(const unsigned long long*)(xwb + base);
    float r0 = sl * bf2f((unsigned short)v)         + (a0[0] + a1[0]) + (a2[0] + a3[0]) + load_f(b1, dt, lane * 4 + 0);
    float r1 = sl * bf2f((unsigned short)(v >> 16)) + (a0[1] + a1[1]) + (a2[1] + a3[1]) + load_f(b1, dt, lane * 4 + 1);
    float r2 = sl * bf2f((unsigned short)(v >> 32)) + (a0[2] + a1[2]) + (a2[2] + a3[2]) + load_f(b1, dt, lane * 4 + 2);
    float r3 = sl * bf2f((unsigned short)(v >> 48)) + (a0[3] + a1[3]) + (a2[3] + a3[3]) + load_f(b1, dt, lane * 4 + 3);
    if (r0 < 0.f) r0 = 0.f;
    if (r1 < 0.f) r1 = 0.f;
    if (r2 < 0.f) r2 = 0.f;
    if (r3 < 0.f) r3 = 0.f;
    unsigned long long o = (unsigned long long)f2bf(r0)
                         | ((unsigned long long)f2bf(r1) << 16)
                         | ((unsigned long long)f2bf(r2) << 32)
                         | ((unsigned long long)f2bf(r3) << 48);
    *(unsigned long long*)(hb + base) = o;
}

// layer-2 aggregation by pull + fused head routing: one wave per node, lane = col
// 8-deep unrolled edge loop for MLP (2B/lane loads -> 8 outstanding rows).
__global__ __launch_bounds__(256) void gather_out(const int* rowptr,
                                                  const unsigned long long* csr,
                                                  const unsigned short* hw2b,
                                                  const void* bc, const void* bk,
                                                  const void* bd,
                                                  const float* dinv,
                                                  const int* flags,
                                                  void* outv) {
    int node = (blockIdx.x * 256 + threadIdx.x) >> 6;
    int lane = threadIdx.x & 63;
    if (node >= NN) return;
    int beg = rowptr[node], end = rowptr[node + 1];
    const unsigned short* hp = hw2b + lane;

    float c0 = 0.f, c1 = 0.f, c2 = 0.f, c3 = 0.f;
    float c4 = 0.f, c5 = 0.f, c6 = 0.f, c7 = 0.f;

    int e = beg;
    for (; e + 8 <= end; e += 8) {
        unsigned long long p0 = csr[e + 0];
        unsigned long long p1 = csr[e + 1];
        unsigned long long p2 = csr[e + 2];
        unsigned long long p3 = csr[e + 3];
        unsigned long long p4 = csr[e + 4];
        unsigned long long p5 = csr[e + 5];
        unsigned long long p6 = csr[e + 6];
        unsigned long long p7 = csr[e + 7];
        float f0 = bf2f(hp[((size_t)(unsigned int)p0) * 64]);
        float f1 = bf2f(hp[((size_t)(unsigned int)p1) * 64]);
        float f2 = bf2f(hp[((size_t)(unsigned int)p2) * 64]);
        float f3 = bf2f(hp[((size_t)(unsigned int)p3) * 64]);
        float f4 = bf2f(hp[((size_t)(unsigned int)p4) * 64]);
        float f5 = bf2f(hp[((size_t)(unsigned int)p5) * 64]);
        float f6 = bf2f(hp[((size_t)(unsigned int)p6) * 64]);
        float f7 = bf2f(hp[((size_t)(unsigned int)p7) * 64]);
        union { unsigned int ui; float ff; } w0, w1, w2, w3, w4, w5, w6, w7;
        w0.ui = (unsigned int)(p0 >> 32);
        w1.ui = (unsigned int)(p1 >> 32);
        w2.ui = (unsigned int)(p2 >> 32);
        w3.ui = (unsigned int)(p3 >> 32);
        w4.ui = (unsigned int)(p4 >> 32);
        w5.ui = (unsigned int)(p5 >> 32);
        w6.ui = (unsigned int)(p6 >> 32);
        w7.ui = (unsigned int)(p7 >> 32);
        c0 += w0.ff * f0;
        c1 += w1.ff * f1;
        c2 += w2.ff * f2;
        c3 += w3.ff * f3;
        c4 += w4.ff * f4;
        c5 += w5.ff * f5;
        c6 += w6.ff * f6;
        c7 += w7.ff * f7;
    }
    for (; e < end; ++e) {
        unsigned long long p = csr[e];
        union { unsigned int ui; float ff; } c;
        c.ui = (unsigned int)(p >> 32);
        c0 += c.ff * bf2f(hp[((size_t)(unsigned int)p) * 64]);
    }
    float acc = ((c0 + c1) + (c2 + c3)) + ((c4 + c5) + (c6 + c7));

    if (lane >= 57) return;
    int dt = flags[1];
    float di = dinv[node];
    float v = di * di * bf2f(hw2b[(size_t)node * 64 + lane]) + acc;
    size_t o;
    if (lane < 40) {
        v += load_f(bc, dt, lane);
        o = (size_t)node * 40 + lane;
    } else if (lane < 56) {
        v += load_f(bk, dt, lane - 40);
        o = (size_t)NN * 40 + (size_t)node * 16 + (lane - 40);
    } else {
        v += load_f(bd, dt, 0);
        o = (size_t)NN * 56 + node;
    }
    if (dt) ((unsigned short*)outv)[o] = f2bf(v);
    else ((float*)outv)[o] = v;
}

extern "C" void kernel_launch(void* const* d_in, const int* in_sizes, int n_in,
                              void* d_out, int out_size, void* d_ws, size_t ws_size,
                              hipStream_t stream) {
    const void* x  = d_in[0];
    const int* ei  = (const int*)d_in[1];
    const void* W1 = d_in[2];
    const void* b1 = d_in[3];
    const void* Wc = d_in[4];
    const void* bc = d_in[5];
    const void* Wk = d_in[6];
    const void* bk = d_in[7];
    const void* Wd = d_in[8];
    const void* bd = d_in[9];

    int E = in_sizes[1] / 2;

    hipError_t herr = hipSuccess;
    hipError_t e;

    // workspace layout (256B-aligned offsets)
    char* ws = (char*)d_ws;
    size_t off = 0;
    int* flags = (int*)(ws + off);                      off += 256;
    float* dinv = (float*)(ws + off);                   off += 400128;
    int* rowptr = (int*)(ws + off);                     off += 400384;   // NN+1
    char* scr = ws + off;                               off += 800256;
    // scratch phase 1 (graph build): degi + cursor
    int* degi = (int*)scr;
    int* cursor = (int*)(scr + 400128);
    // scratch phase 2 (after fill_csr, degi/cursor dead): split weight tables
    unsigned short* w1t_hi = (unsigned short*)scr;                  // 256*512*2 = 262144
    unsigned short* w1t_lo = (unsigned short*)(scr + 262144);       // 262144
    unsigned short* wct_hi = (unsigned short*)(scr + 524288);       // 64*256*2 = 32768
    unsigned short* wct_lo = (unsigned short*)(scr + 557056);       // 32768 (total 589824 <= 800256)
    unsigned long long* csr = (unsigned long long*)(ws + off); off += (size_t)E * 8;
    unsigned short* xwb = (unsigned short*)(ws + off);  off += (size_t)NN * 256 * 2;
    unsigned short* hb = (unsigned short*)(ws + off);   off += (size_t)NN * 256 * 2;
    unsigned short* hw2b = (unsigned short*)(ws + off); off += (size_t)NN * 64 * 2;

    int ws_bad = (off > ws_size) ? 1 : 0;

    if (!ws_bad) {
        e = hipMemsetAsync(degi, 0, (size_t)NN * 4, stream);
        if (herr == hipSuccess && e != hipSuccess) herr = e;
        e = hipMemsetAsync(cursor, 0, (size_t)NN * 4, stream);
        if (herr == hipSuccess && e != hipSuccess) herr = e;

        probe_fmt<<<1, 64, 0, stream>>>(ei, (const unsigned short*)x, flags);
        count_deg_i<<<(E + 255) / 256, 256, 0, stream>>>(ei, flags, degi, E);
        make_dinv<<<(NN + 255) / 256, 256, 0, stream>>>(degi, dinv);
        scan_rowptr<<<1, 1024, 0, stream>>>(degi, rowptr);
        fill_csr<<<(E + 255) / 256, 256, 0, stream>>>(ei, flags, dinv, rowptr,
                                                      cursor, csr, E);

        // degi/cursor dead from here; build transposed split-bf16 weight tables
        prep_w1t<<<512, 256, 0, stream>>>(W1, flags, w1t_hi, w1t_lo);
        prep_wcat<<<64, 256, 0, stream>>>(Wc, Wk, Wd, flags, wct_hi, wct_lo);

        // layer 1: xw = x @ W1   (M=100000, K=512, N=256), MFMA split-bf16
        {
            dim3 grid((NN + 127) / 128, 2);
            gemm_mfma<128, 4><<<grid, 256, 0, stream>>>(x, w1t_hi, w1t_lo, xwb,
                                                        NN, 256, 512, flags, 0);
        }
        gather_h<<<(NN + 3) / 4, 256, 0, stream>>>(rowptr, csr, xwb, b1, dinv,
                                                   flags, hb);

        // layer 2: hw2 = h @ Wcat   (M=100000, K=256, N=64), A already bf16
        {
            dim3 grid((NN + 127) / 128, 1);
            gemm_mfma<64, 2><<<grid, 256, 0, stream>>>(hb, wct_hi, wct_lo, hw2b,
                                                       NN, 64, 256, flags, 2);
        }
        gather_out<<<(NN + 3) / 4, 256, 0, stream>>>(rowptr, csr, hw2b, bc, bk, bd,
                                                     dinv, flags, d_out);
    }

    e = hipGetLastError();
    if (herr == hipSuccess && e != hipSuccess) herr = e;

    if (herr != hipSuccess) {
        (void)hipMemsetAsync(d_out, 0x41 + ((int)herr & 7), 128, stream);
    }
    if (ws_bad) {
        (void)hipMemsetAsync(d_out, 0x58, 128, stream);
    }
}

// Round 4
// 1282.063 us; speedup vs baseline: 1.5894x; 1.0495x over previous
//
#include <hip/hip_runtime.h>

#define NN 100000

typedef __attribute__((ext_vector_type(8))) __bf16 bf16x8;
typedef __attribute__((ext_vector_type(8))) unsigned short ushort8v;
typedef __attribute__((ext_vector_type(4))) float f32x4;

__device__ __forceinline__ float bf2f(unsigned short u) {
    union { unsigned int ui; float f; } c;
    c.ui = ((unsigned int)u) << 16;
    return c.f;
}

__device__ __forceinline__ unsigned short f2bf(float f) {
    union { float ff; unsigned int ui; } c;
    c.ff = f;
    unsigned int u = c.ui;
    u += 0x7FFFu + ((u >> 16) & 1u);   // round-to-nearest-even
    return (unsigned short)(u >> 16);
}

// truncation split: x = hi + resid, hi = bf16-truncate(x)
__device__ __forceinline__ unsigned short trunc_hi(float x, float& resid) {
    union { float f; unsigned int u; } c, h;
    c.f = x;
    h.u = c.u & 0xFFFF0000u;
    resid = x - h.f;
    return (unsigned short)(c.u >> 16);
}

__device__ __forceinline__ unsigned short trunc_bits(float x) {
    union { float f; unsigned int u; } c;
    c.f = x;
    return (unsigned short)(c.u >> 16);
}

// async global->LDS, 16B per lane; LDS dst is wave-uniform base + lane*16 (HW).
// NOTE: builtin is strictly type-checked; strip const and cast via plain void*.
__device__ __forceinline__ void gload_lds16(const void* g, void* l) {
    void* gnc = (void*)g;
    __builtin_amdgcn_global_load_lds((__attribute__((address_space(1))) void*)gnc,
                                     (__attribute__((address_space(3))) void*)l,
                                     16, 0, 0);
}

__global__ void MultiTaskGCN_37623913513359_kernel() {}

// flags[0]: edge index format, 1 = int64, 0 = int32
// flags[1]: float dtype, 1 = bf16-backed, 0 = fp32-backed
__global__ void probe_fmt(const int* ei, const unsigned short* x, int* flags) {
    if (blockIdx.x != 0 || threadIdx.x != 0) return;
    int any = 0;
    for (int i = 0; i < 64; ++i) any |= ei[2 * i + 1];
    flags[0] = (any == 0) ? 1 : 0;
    int bf = 1;
    for (int i = 0; i < 512; ++i) {
        float v = bf2f(x[2 * i]);
        float av = v < 0.0f ? -v : v;
        if (!(v == v) || av > 1.0e6f) { bf = 0; break; }
    }
    flags[1] = bf;
}

__device__ __forceinline__ int edge_src(const int* ei, int is64, int e) {
    if (is64) return ei[2 * e];
    return ei[e];
}
__device__ __forceinline__ int edge_dst(const int* ei, int is64, int e, int E) {
    if (is64) return ei[2 * (E + e)];
    return ei[E + e];
}

__device__ __forceinline__ float load_f(const void* p, int dt, size_t i) {
    if (dt) return bf2f(((const unsigned short*)p)[i]);
    return ((const float*)p)[i];
}

__global__ __launch_bounds__(256) void count_deg_i(const int* ei, const int* flags,
                                                   int* degi, int E) {
    int t = blockIdx.x * 256 + threadIdx.x;
    if (t >= E) return;
    int is64 = flags[0];
    int s = edge_src(ei, is64, t);
    int d = edge_dst(ei, is64, t, E);
    if (((unsigned)s) >= NN || ((unsigned)d) >= NN) return;
    atomicAdd(&degi[d], 1);
}

__global__ __launch_bounds__(256) void make_dinv(const int* degi, float* dinv) {
    int i = blockIdx.x * 256 + threadIdx.x;
    if (i < NN) dinv[i] = rsqrtf((float)degi[i] + 1.0f);   // +1 self loop
}

// single-block exclusive scan of degi -> rowptr (NN+1 entries)
__global__ __launch_bounds__(1024) void scan_rowptr(const int* degi, int* rowptr) {
    __shared__ int part[1024];
    int tid = threadIdx.x;
    const int chunk = (NN + 1023) / 1024;   // 98
    int base = tid * chunk;
    int s = 0;
    for (int j = 0; j < chunk; ++j) {
        int i = base + j;
        if (i < NN) s += degi[i];
    }
    part[tid] = s;
    __syncthreads();
    for (int off = 1; off < 1024; off <<= 1) {
        int v = (tid >= off) ? part[tid - off] : 0;
        __syncthreads();
        part[tid] += v;
        __syncthreads();
    }
    int run = (tid == 0) ? 0 : part[tid - 1];
    for (int j = 0; j < chunk; ++j) {
        int i = base + j;
        if (i < NN) {
            rowptr[i] = run;
            run += degi[i];
        }
    }
    if (tid == 1023) rowptr[NN] = part[1023];
}

// fill CSR: packed entry = (w_bits << 32) | src
__global__ __launch_bounds__(256) void fill_csr(const int* ei, const int* flags,
                                                const float* dinv, const int* rowptr,
                                                int* cursor, unsigned long long* csr,
                                                int E) {
    int t = blockIdx.x * 256 + threadIdx.x;
    if (t >= E) return;
    int is64 = flags[0];
    int s = edge_src(ei, is64, t);
    int d = edge_dst(ei, is64, t, E);
    if (((unsigned)s) >= NN || ((unsigned)d) >= NN) return;
    int pos = rowptr[d] + atomicAdd(&cursor[d], 1);
    float w = dinv[s] * dinv[d];
    union { float ff; unsigned int ui; } c;
    c.ff = w;
    csr[pos] = ((unsigned long long)c.ui << 32) | (unsigned int)s;
}

// W1 (row-major [512][256], fp32 or bf16) -> W1T hi/lo bf16 [256 n][512 k]
__global__ __launch_bounds__(256) void prep_w1t(const void* W1, const int* flags,
                                                unsigned short* hi, unsigned short* lo) {
    int t = blockIdx.x * 256 + threadIdx.x;
    if (t >= 256 * 512) return;
    int n = t >> 9, k = t & 511;
    float v = load_f(W1, flags[1], (size_t)k * 256 + n);
    float r;
    hi[t] = trunc_hi(v, r);
    lo[t] = trunc_bits(r);
}

// [Wc | Wk | Wd | 0] -> WcatT hi/lo bf16 [64 n][256 k]
__global__ __launch_bounds__(256) void prep_wcat(const void* Wc, const void* Wk,
                                                 const void* Wd, const int* flags,
                                                 unsigned short* hi, unsigned short* lo) {
    int t = blockIdx.x * 256 + threadIdx.x;
    if (t >= 64 * 256) return;
    int n = t >> 8, k = t & 255;
    int dt = flags[1];
    float v = 0.0f;
    if (n < 40) v = load_f(Wc, dt, (size_t)k * 40 + n);
    else if (n < 56) v = load_f(Wk, dt, (size_t)k * 16 + (n - 40));
    else if (n == 56) v = load_f(Wd, dt, k);
    float r;
    hi[t] = trunc_hi(v, r);
    lo[t] = trunc_bits(r);
}

// x fp32 [NN][512] -> xs: per 8-elem group, [8x hi bf16 (16B)][8x lo bf16 (16B)]
// row stride = 512*4 B (same as x). No-op for bf16 input.
__global__ __launch_bounds__(256) void split_x(const float* x, unsigned char* xs,
                                               const int* flags, long long ngrp) {
    if (flags[1]) return;
    long long i0 = (long long)blockIdx.x * 256 + threadIdx.x;
    long long stride = (long long)gridDim.x * 256;
    for (long long g = i0; g < ngrp; g += stride) {
        const float* p = x + g * 8;
        f32x4 v0 = *(const f32x4*)p;
        f32x4 v1 = *(const f32x4*)(p + 4);
        ushort8v h, l;
        float r;
#pragma unroll
        for (int j = 0; j < 4; ++j) {
            h[j] = trunc_hi(v0[j], r);
            l[j] = trunc_bits(r);
        }
#pragma unroll
        for (int j = 0; j < 4; ++j) {
            h[4 + j] = trunc_hi(v1[j], r);
            l[4 + j] = trunc_bits(r);
        }
        *(ushort8v*)(xs + g * 32) = h;
        *(ushort8v*)(xs + g * 32 + 16) = l;
    }
}

// ---------------- MFMA GEMM v2: global_load_lds staging ----------------
// C[M,N](bf16) = A[M,K] @ B[K,N]; B pre-transposed+split BT_hi/BT_lo [N][K] bf16.
// A addressing modes:
//   amode=0, dt=0: A = xs (interleaved hi/lo groups), 3-product split GEMM
//   amode=0, dt=1: A = x  (bf16 row-major), hi only
//   amode=2:       A = bf16 row-major internal buffer, hi only
// LDS layout (k-group-major): panel[kg][row] of 16B chunks -> conflict-free
// ds_read_b128 frags AND linear global_load_lds writes.

template<int BN, int NF>
__global__ __launch_bounds__(256, 3) void gemm_gl(const void* A, const void* Axs,
                                                  const unsigned short* BTh,
                                                  const unsigned short* BTl,
                                                  unsigned short* C,
                                                  int M, int N, int K,
                                                  const int* flags, int amode) {
    constexpr int BM = 128;
    constexpr int HB = BN / 64;         // B col-halves
    // [Ash | Asl | Bsh | Bsl] in 16B units
    __shared__ ushort8v smem[4 * BM + 4 * BM + 4 * BN + 4 * BN];
    ushort8v* Ash = smem;
    ushort8v* Asl = smem + 4 * BM;
    ushort8v* Bsh = smem + 8 * BM;
    ushort8v* Bsl = smem + 8 * BM + 4 * BN;

    const int tid = threadIdx.x;
    const int lane = tid & 63;
    const int wid = tid >> 6;
    const int wm = wid >> 1;            // 2x2 wave grid, wave tile 64 x (NF*16)
    const int wn = wid & 1;
    const int dt = flags[1];

    const unsigned char* Ab;
    int rowbytes, gstep, alo;
    if (amode == 0 && dt == 0) {
        Ab = (const unsigned char*)Axs; rowbytes = K * 4; gstep = 32; alo = 1;
    } else {
        Ab = (const unsigned char*)A;   rowbytes = K * 2; gstep = 16; alo = 0;
    }
    const int blo = (dt == 0) ? 1 : 0;

    const int m0 = blockIdx.x * BM;
    const int n0 = blockIdx.y * BN;

    f32x4 zero = {0.0f, 0.0f, 0.0f, 0.0f};
    f32x4 acc[4][NF];
#pragma unroll
    for (int i = 0; i < 4; ++i)
#pragma unroll
        for (int j = 0; j < NF; ++j) acc[i][j] = zero;

    const int nT = K >> 5;              // K-steps of 32
    for (int t = 0; t < nT; ++t) {
        const int k0 = t << 5;
        const int G0 = t << 2;
        // stage A (8 gload ops spread over 4 waves; q loop <=2 iters)
        for (int q = wid; q < 8; q += 4) {
            int kg = q >> 1, hf = q & 1;
            int row = m0 + hf * 64 + lane;
            if (row >= M) row = M - 1;
            const unsigned char* g = Ab + (size_t)row * rowbytes + (size_t)(G0 + kg) * gstep;
            gload_lds16(g, Ash + kg * BM + hf * 64);
            if (alo) gload_lds16(g + 16, Asl + kg * BM + hf * 64);
        }
        // stage B (4*HB gload ops spread over 4 waves)
        for (int q = wid; q < 4 * HB; q += 4) {
            int kg = q / HB, hf = q % HB;
            int col = n0 + hf * 64 + lane;
            const unsigned short* gh = BTh + (size_t)col * K + k0 + kg * 8;
            gload_lds16(gh, Bsh + kg * BN + hf * 64);
            if (blo) gload_lds16(BTl + (size_t)col * K + k0 + kg * 8, Bsl + kg * BN + hf * 64);
        }
        __syncthreads();   // compiler drains vmcnt(0) before barrier -> LDS ready

        {
            const int lr = lane & 15;
            const int lk = lane >> 4;
            bf16x8 ah[4], al[4];
#pragma unroll
            for (int i = 0; i < 4; ++i) {
                ah[i] = *(const bf16x8*)&Ash[lk * BM + wm * 64 + i * 16 + lr];
                if (alo) al[i] = *(const bf16x8*)&Asl[lk * BM + wm * 64 + i * 16 + lr];
            }
            bf16x8 bh[NF], bl[NF];
#pragma unroll
            for (int j = 0; j < NF; ++j) {
                bh[j] = *(const bf16x8*)&Bsh[lk * BN + wn * (NF * 16) + j * 16 + lr];
                if (blo) bl[j] = *(const bf16x8*)&Bsl[lk * BN + wn * (NF * 16) + j * 16 + lr];
            }
#pragma unroll
            for (int i = 0; i < 4; ++i) {
#pragma unroll
                for (int j = 0; j < NF; ++j) {
                    acc[i][j] = __builtin_amdgcn_mfma_f32_16x16x32_bf16(ah[i], bh[j], acc[i][j], 0, 0, 0);
                    if (blo) acc[i][j] = __builtin_amdgcn_mfma_f32_16x16x32_bf16(ah[i], bl[j], acc[i][j], 0, 0, 0);
                    if (alo) acc[i][j] = __builtin_amdgcn_mfma_f32_16x16x32_bf16(al[i], bh[j], acc[i][j], 0, 0, 0);
                }
            }
        }
        __syncthreads();   // all frag reads done before next stage overwrites
    }

    // ---- epilogue: acc -> LDS [BM][BN] bf16 -> coalesced 16B stores ----
    unsigned short* cs = (unsigned short*)smem;   // BM*BN*2 <= sizeof(smem)
    const int lr = lane & 15;
    const int lq = lane >> 4;
#pragma unroll
    for (int i = 0; i < 4; ++i) {
#pragma unroll
        for (int j = 0; j < NF; ++j) {
#pragma unroll
            for (int rr = 0; rr < 4; ++rr) {
                int row = wm * 64 + i * 16 + lq * 4 + rr;
                int col = wn * (NF * 16) + j * 16 + lr;
                cs[row * BN + col] = f2bf(acc[i][j][rr]);
            }
        }
    }
    __syncthreads();
    constexpr int TOTAL = BM * BN;
#pragma unroll
    for (int base = 0; base < TOTAL; base += 2048) {
        int idx = base + tid * 8;
        int r = idx / BN;
        int c = idx % BN;
        int grow = m0 + r;
        if (grow < M) {
            *(ushort8v*)(C + (size_t)grow * N + n0 + c) = *(const ushort8v*)(cs + idx);
        }
    }
}

// ---------------- legacy reg-staged MFMA GEMM (fallback when ws too small) ----

template<int NB>
struct StageRegs {
    ushort8v ah[2], al[2], bh[NB], bl[NB];
};

template<int NB>
__device__ __forceinline__ StageRegs<NB> stage_load(const void* A, const unsigned short* BTh,
                                                    const unsigned short* BTl, int M, int K,
                                                    int m0, int n0, int k0,
                                                    int lane, int wid, int adt, bool blo) {
    StageRegs<NB> s;
#pragma unroll
    for (int half = 0; half < 2; ++half) {
        int gr = m0 + lane + half * 64;
        if (gr >= M) gr = M - 1;
        if (adt == 0) {
            const float* ap = (const float*)A + (size_t)gr * K + k0 + wid * 8;
            f32x4 v0 = *(const f32x4*)ap;
            f32x4 v1 = *(const f32x4*)(ap + 4);
            ushort8v h, l;
#pragma unroll
            for (int j = 0; j < 4; ++j) {
                float r;
                h[j] = trunc_hi(v0[j], r);
                l[j] = trunc_bits(r);
            }
#pragma unroll
            for (int j = 0; j < 4; ++j) {
                float r;
                h[4 + j] = trunc_hi(v1[j], r);
                l[4 + j] = trunc_bits(r);
            }
            s.ah[half] = h;
            s.al[half] = l;
        } else {
            s.ah[half] = *(const ushort8v*)((const unsigned short*)A + (size_t)gr * K + k0 + wid * 8);
        }
    }
#pragma unroll
    for (int nb = 0; nb < NB; ++nb) {
        size_t o = (size_t)(n0 + lane + nb * 64) * K + k0 + wid * 8;
        s.bh[nb] = *(const ushort8v*)(BTh + o);
        if (blo) s.bl[nb] = *(const ushort8v*)(BTl + o);
    }
    return s;
}

template<int BM, int BN, int NB>
__device__ __forceinline__ void stage_write(ushort8v (&As)[2][4][BM], ushort8v (&Bs)[2][4][BN],
                                            const StageRegs<NB>& s, int lane, int wid,
                                            bool alo, bool blo) {
    As[0][wid][lane] = s.ah[0];
    As[0][wid][lane + 64] = s.ah[1];
    if (alo) {
        As[1][wid][lane] = s.al[0];
        As[1][wid][lane + 64] = s.al[1];
    }
#pragma unroll
    for (int nb = 0; nb < NB; ++nb) {
        Bs[0][wid][lane + nb * 64] = s.bh[nb];
        if (blo) Bs[1][wid][lane + nb * 64] = s.bl[nb];
    }
}

template<int BM, int BN, int NF>
__device__ __forceinline__ void mfma_step(const ushort8v (&As)[2][4][BM],
                                          const ushort8v (&Bs)[2][4][BN],
                                          f32x4 (&acc)[4][NF],
                                          int wm, int wn, int lane, bool alo, bool blo) {
    const int lr = lane & 15;
    const int lk = lane >> 4;
    bf16x8 ah[4], al[4];
#pragma unroll
    for (int i = 0; i < 4; ++i) {
        ah[i] = *(const bf16x8*)&As[0][lk][wm * 64 + i * 16 + lr];
        if (alo) al[i] = *(const bf16x8*)&As[1][lk][wm * 64 + i * 16 + lr];
    }
    bf16x8 bh[NF], bl[NF];
#pragma unroll
    for (int j = 0; j < NF; ++j) {
        bh[j] = *(const bf16x8*)&Bs[0][lk][wn * (BN / 2) + j * 16 + lr];
        if (blo) bl[j] = *(const bf16x8*)&Bs[1][lk][wn * (BN / 2) + j * 16 + lr];
    }
#pragma unroll
    for (int i = 0; i < 4; ++i) {
#pragma unroll
        for (int j = 0; j < NF; ++j) {
            acc[i][j] = __builtin_amdgcn_mfma_f32_16x16x32_bf16(ah[i], bh[j], acc[i][j], 0, 0, 0);
            if (blo) acc[i][j] = __builtin_amdgcn_mfma_f32_16x16x32_bf16(ah[i], bl[j], acc[i][j], 0, 0, 0);
            if (alo) acc[i][j] = __builtin_amdgcn_mfma_f32_16x16x32_bf16(al[i], bh[j], acc[i][j], 0, 0, 0);
        }
    }
}

template<int BN, int NF>
__global__ __launch_bounds__(256) void gemm_mfma(const void* A, const unsigned short* BTh,
                                                 const unsigned short* BTl, unsigned short* C,
                                                 int M, int N, int K, const int* flags, int amode) {
    constexpr int BM = 128;
    constexpr int NB = BN / 64;
    __shared__ ushort8v As[2][4][BM];
    __shared__ ushort8v Bs[2][4][BN];

    const int tid = threadIdx.x;
    const int lane = tid & 63;
    const int wid = tid >> 6;
    const int wm = wid >> 1;
    const int wn = wid & 1;
    const int dt = flags[1];
    const int adt = (amode == 0) ? dt : 1;
    const bool alo = (adt == 0);
    const bool blo = (dt == 0);
    const int m0 = blockIdx.x * BM;
    const int n0 = blockIdx.y * BN;

    f32x4 zero = {0.0f, 0.0f, 0.0f, 0.0f};
    f32x4 acc[4][NF];
#pragma unroll
    for (int i = 0; i < 4; ++i)
#pragma unroll
        for (int j = 0; j < NF; ++j) acc[i][j] = zero;

    StageRegs<NB> sA = stage_load<NB>(A, BTh, BTl, M, K, m0, n0, 0, lane, wid, adt, blo);
    const int nT = K >> 5;
    for (int t = 0; t < nT; t += 2) {
        __syncthreads();
        stage_write<BM, BN, NB>(As, Bs, sA, lane, wid, alo, blo);
        __syncthreads();
        StageRegs<NB> sB = stage_load<NB>(A, BTh, BTl, M, K, m0, n0, (t + 1) << 5, lane, wid, adt, blo);
        mfma_step<BM, BN, NF>(As, Bs, acc, wm, wn, lane, alo, blo);
        __syncthreads();
        stage_write<BM, BN, NB>(As, Bs, sB, lane, wid, alo, blo);
        __syncthreads();
        if (t + 2 < nT)
            sA = stage_load<NB>(A, BTh, BTl, M, K, m0, n0, (t + 2) << 5, lane, wid, adt, blo);
        mfma_step<BM, BN, NF>(As, Bs, acc, wm, wn, lane, alo, blo);
    }

    const int lr = lane & 15;
    const int lq = lane >> 4;
#pragma unroll
    for (int i = 0; i < 4; ++i) {
#pragma unroll
        for (int rr = 0; rr < 4; ++rr) {
            int row = m0 + wm * 64 + i * 16 + lq * 4 + rr;
            if (row < M) {
#pragma unroll
                for (int j = 0; j < NF; ++j) {
                    int col = n0 + wn * (BN / 2) + j * 16 + lr;
                    C[(size_t)row * N + col] = f2bf(acc[i][j][rr]);
                }
            }
        }
    }
}

// layer-1 aggregation by pull + fused epilogue: one wave per destination node.
// 4-deep unrolled edge loop (MLP: 4 random 512B row-gathers in flight per wave).
__global__ __launch_bounds__(256) void gather_h(const int* rowptr,
                                                const unsigned long long* csr,
                                                const unsigned short* xwb,
                                                const void* b1,
                                                const float* dinv,
                                                const int* flags,
                                                unsigned short* hb) {
    int node = (blockIdx.x * 256 + threadIdx.x) >> 6;
    int lane = threadIdx.x & 63;
    if (node >= NN) return;
    int beg = rowptr[node], end = rowptr[node + 1];
    const unsigned short* xp = xwb + (size_t)lane * 4;

    float a0[4] = {0.f, 0.f, 0.f, 0.f};
    float a1[4] = {0.f, 0.f, 0.f, 0.f};
    float a2[4] = {0.f, 0.f, 0.f, 0.f};
    float a3[4] = {0.f, 0.f, 0.f, 0.f};

    int e = beg;
    for (; e + 4 <= end; e += 4) {
        unsigned long long p0 = csr[e + 0];
        unsigned long long p1 = csr[e + 1];
        unsigned long long p2 = csr[e + 2];
        unsigned long long p3 = csr[e + 3];
        unsigned long long v0 = *(const unsigned long long*)(xp + ((size_t)(unsigned int)p0) * 256);
        unsigned long long v1 = *(const unsigned long long*)(xp + ((size_t)(unsigned int)p1) * 256);
        unsigned long long v2 = *(const unsigned long long*)(xp + ((size_t)(unsigned int)p2) * 256);
        unsigned long long v3 = *(const unsigned long long*)(xp + ((size_t)(unsigned int)p3) * 256);
        union { unsigned int ui; float ff; } w0, w1, w2, w3;
        w0.ui = (unsigned int)(p0 >> 32);
        w1.ui = (unsigned int)(p1 >> 32);
        w2.ui = (unsigned int)(p2 >> 32);
        w3.ui = (unsigned int)(p3 >> 32);
        a0[0] += w0.ff * bf2f((unsigned short)v0);
        a0[1] += w0.ff * bf2f((unsigned short)(v0 >> 16));
        a0[2] += w0.ff * bf2f((unsigned short)(v0 >> 32));
        a0[3] += w0.ff * bf2f((unsigned short)(v0 >> 48));
        a1[0] += w1.ff * bf2f((unsigned short)v1);
        a1[1] += w1.ff * bf2f((unsigned short)(v1 >> 16));
        a1[2] += w1.ff * bf2f((unsigned short)(v1 >> 32));
        a1[3] += w1.ff * bf2f((unsigned short)(v1 >> 48));
        a2[0] += w2.ff * bf2f((unsigned short)v2);
        a2[1] += w2.ff * bf2f((unsigned short)(v2 >> 16));
        a2[2] += w2.ff * bf2f((unsigned short)(v2 >> 32));
        a2[3] += w2.ff * bf2f((unsigned short)(v2 >> 48));
        a3[0] += w3.ff * bf2f((unsigned short)v3);
        a3[1] += w3.ff * bf2f((unsigned short)(v3 >> 16));
        a3[2] += w3.ff * bf2f((unsigned short)(v3 >> 32));
        a3[3] += w3.ff * bf2f((unsigned short)(v3 >> 48));
    }
    for (; e < end; ++e) {
        unsigned long long p = csr[e];
        union { unsigned int ui; float ff; } c;
        c.ui = (unsigned int)(p >> 32);
        unsigned long long v = *(const unsigned long long*)(xp + ((size_t)(unsigned int)p) * 256);
        a0[0] += c.ff * bf2f((unsigned short)v);
        a0[1] += c.ff * bf2f((unsigned short)(v >> 16));
        a0[2] += c.ff * bf2f((unsigned short)(v >> 32));
        a0[3] += c.ff * bf2f((unsigned short)(v >> 48));
    }

    int dt = flags[1];
    float di = dinv[node];
    float sl = di * di;
    size_t base = (size_t)node * 256 + lane * 4;
    unsigned long long v = *(const unsigned long long*)(xwb + base);
    float r0 = sl * bf2f((unsigned short)v)         + (a0[0] + a1[0]) + (a2[0] + a3[0]) + load_f(b1, dt, lane * 4 + 0);
    float r1 = sl * bf2f((unsigned short)(v >> 16)) + (a0[1] + a1[1]) + (a2[1] + a3[1]) + load_f(b1, dt, lane * 4 + 1);
    float r2 = sl * bf2f((unsigned short)(v >> 32)) + (a0[2] + a1[2]) + (a2[2] + a3[2]) + load_f(b1, dt, lane * 4 + 2);
    float r3 = sl * bf2f((unsigned short)(v >> 48)) + (a0[3] + a1[3]) + (a2[3] + a3[3]) + load_f(b1, dt, lane * 4 + 3);
    if (r0 < 0.f) r0 = 0.f;
    if (r1 < 0.f) r1 = 0.f;
    if (r2 < 0.f) r2 = 0.f;
    if (r3 < 0.f) r3 = 0.f;
    unsigned long long o = (unsigned long long)f2bf(r0)
                         | ((unsigned long long)f2bf(r1) << 16)
                         | ((unsigned long long)f2bf(r2) << 32)
                         | ((unsigned long long)f2bf(r3) << 48);
    *(unsigned long long*)(hb + base) = o;
}

// layer-2 aggregation by pull + fused head routing: one wave per node, lane = col
// 8-deep unrolled edge loop for MLP.
__global__ __launch_bounds__(256) void gather_out(const int* rowptr,
                                                  const unsigned long long* csr,
                                                  const unsigned short* hw2b,
                                                  const void* bc, const void* bk,
                                                  const void* bd,
                                                  const float* dinv,
                                                  const int* flags,
                                                  void* outv) {
    int node = (blockIdx.x * 256 + threadIdx.x) >> 6;
    int lane = threadIdx.x & 63;
    if (node >= NN) return;
    int beg = rowptr[node], end = rowptr[node + 1];
    const unsigned short* hp = hw2b + lane;

    float c0 = 0.f, c1 = 0.f, c2 = 0.f, c3 = 0.f;
    float c4 = 0.f, c5 = 0.f, c6 = 0.f, c7 = 0.f;

    int e = beg;
    for (; e + 8 <= end; e += 8) {
        unsigned long long p0 = csr[e + 0];
        unsigned long long p1 = csr[e + 1];
        unsigned long long p2 = csr[e + 2];
        unsigned long long p3 = csr[e + 3];
        unsigned long long p4 = csr[e + 4];
        unsigned long long p5 = csr[e + 5];
        unsigned long long p6 = csr[e + 6];
        unsigned long long p7 = csr[e + 7];
        float f0 = bf2f(hp[((size_t)(unsigned int)p0) * 64]);
        float f1 = bf2f(hp[((size_t)(unsigned int)p1) * 64]);
        float f2 = bf2f(hp[((size_t)(unsigned int)p2) * 64]);
        float f3 = bf2f(hp[((size_t)(unsigned int)p3) * 64]);
        float f4 = bf2f(hp[((size_t)(unsigned int)p4) * 64]);
        float f5 = bf2f(hp[((size_t)(unsigned int)p5) * 64]);
        float f6 = bf2f(hp[((size_t)(unsigned int)p6) * 64]);
        float f7 = bf2f(hp[((size_t)(unsigned int)p7) * 64]);
        union { unsigned int ui; float ff; } w0, w1, w2, w3, w4, w5, w6, w7;
        w0.ui = (unsigned int)(p0 >> 32);
        w1.ui = (unsigned int)(p1 >> 32);
        w2.ui = (unsigned int)(p2 >> 32);
        w3.ui = (unsigned int)(p3 >> 32);
        w4.ui = (unsigned int)(p4 >> 32);
        w5.ui = (unsigned int)(p5 >> 32);
        w6.ui = (unsigned int)(p6 >> 32);
        w7.ui = (unsigned int)(p7 >> 32);
        c0 += w0.ff * f0;
        c1 += w1.ff * f1;
        c2 += w2.ff * f2;
        c3 += w3.ff * f3;
        c4 += w4.ff * f4;
        c5 += w5.ff * f5;
        c6 += w6.ff * f6;
        c7 += w7.ff * f7;
    }
    for (; e < end; ++e) {
        unsigned long long p = csr[e];
        union { unsigned int ui; float ff; } c;
        c.ui = (unsigned int)(p >> 32);
        c0 += c.ff * bf2f(hp[((size_t)(unsigned int)p) * 64]);
    }
    float acc = ((c0 + c1) + (c2 + c3)) + ((c4 + c5) + (c6 + c7));

    if (lane >= 57) return;
    int dt = flags[1];
    float di = dinv[node];
    float v = di * di * bf2f(hw2b[(size_t)node * 64 + lane]) + acc;
    size_t o;
    if (lane < 40) {
        v += load_f(bc, dt, lane);
        o = (size_t)node * 40 + lane;
    } else if (lane < 56) {
        v += load_f(bk, dt, lane - 40);
        o = (size_t)NN * 40 + (size_t)node * 16 + (lane - 40);
    } else {
        v += load_f(bd, dt, 0);
        o = (size_t)NN * 56 + node;
    }
    if (dt) ((unsigned short*)outv)[o] = f2bf(v);
    else ((float*)outv)[o] = v;
}

extern "C" void kernel_launch(void* const* d_in, const int* in_sizes, int n_in,
                              void* d_out, int out_size, void* d_ws, size_t ws_size,
                              hipStream_t stream) {
    const void* x  = d_in[0];
    const int* ei  = (const int*)d_in[1];
    const void* W1 = d_in[2];
    const void* b1 = d_in[3];
    const void* Wc = d_in[4];
    const void* bc = d_in[5];
    const void* Wk = d_in[6];
    const void* bk = d_in[7];
    const void* Wd = d_in[8];
    const void* bd = d_in[9];

    int E = in_sizes[1] / 2;

    hipError_t herr = hipSuccess;
    hipError_t e;

    // workspace layout (256B-aligned offsets)
    char* ws = (char*)d_ws;
    size_t off = 0;
    int* flags = (int*)(ws + off);                      off += 256;
    float* dinv = (float*)(ws + off);                   off += 400128;
    int* rowptr = (int*)(ws + off);                     off += 400384;   // NN+1
    char* scr = ws + off;                               off += 800256;
    // scratch phase 1 (graph build): degi + cursor
    int* degi = (int*)scr;
    int* cursor = (int*)(scr + 400128);
    // scratch phase 2 (after fill_csr): split weight tables
    unsigned short* w1t_hi = (unsigned short*)scr;
    unsigned short* w1t_lo = (unsigned short*)(scr + 262144);
    unsigned short* wct_hi = (unsigned short*)(scr + 524288);
    unsigned short* wct_lo = (unsigned short*)(scr + 557056);
    unsigned long long* csr = (unsigned long long*)(ws + off); off += (size_t)E * 8;
    unsigned short* xwb = (unsigned short*)(ws + off);  off += (size_t)NN * 256 * 2;
    unsigned short* hb = (unsigned short*)(ws + off);   off += (size_t)NN * 256 * 2;
    unsigned short* hw2b = (unsigned short*)(ws + off); off += (size_t)NN * 64 * 2;

    int ws_bad = (off > ws_size) ? 1 : 0;

    // optional fast-path buffer: interleaved hi/lo bf16 split of x (204.8 MB)
    unsigned char* xs = (unsigned char*)(ws + off);
    size_t xs_bytes = (size_t)NN * 512 * 4;
    int fast = (!ws_bad && (off + xs_bytes) <= ws_size) ? 1 : 0;

    if (!ws_bad) {
        e = hipMemsetAsync(degi, 0, (size_t)NN * 4, stream);
        if (herr == hipSuccess && e != hipSuccess) herr = e;
        e = hipMemsetAsync(cursor, 0, (size_t)NN * 4, stream);
        if (herr == hipSuccess && e != hipSuccess) herr = e;

        probe_fmt<<<1, 64, 0, stream>>>(ei, (const unsigned short*)x, flags);
        count_deg_i<<<(E + 255) / 256, 256, 0, stream>>>(ei, flags, degi, E);
        make_dinv<<<(NN + 255) / 256, 256, 0, stream>>>(degi, dinv);
        scan_rowptr<<<1, 1024, 0, stream>>>(degi, rowptr);
        fill_csr<<<(E + 255) / 256, 256, 0, stream>>>(ei, flags, dinv, rowptr,
                                                      cursor, csr, E);

        // degi/cursor dead from here
        prep_w1t<<<512, 256, 0, stream>>>(W1, flags, w1t_hi, w1t_lo);
        prep_wcat<<<64, 256, 0, stream>>>(Wc, Wk, Wd, flags, wct_hi, wct_lo);

        // layer 1: xw = x @ W1   (M=100000, K=512, N=256)
        if (fast) {
            split_x<<<4096, 256, 0, stream>>>((const float*)x, xs, flags,
                                              (long long)NN * 512 / 8);
            dim3 grid((NN + 127) / 128, 2);
            gemm_gl<128, 4><<<grid, 256, 0, stream>>>(x, xs, w1t_hi, w1t_lo, xwb,
                                                      NN, 256, 512, flags, 0);
        } else {
            dim3 grid((NN + 127) / 128, 2);
            gemm_mfma<128, 4><<<grid, 256, 0, stream>>>(x, w1t_hi, w1t_lo, xwb,
                                                        NN, 256, 512, flags, 0);
        }
        gather_h<<<(NN + 3) / 4, 256, 0, stream>>>(rowptr, csr, xwb, b1, dinv,
                                                   flags, hb);

        // layer 2: hw2 = h @ Wcat   (M=100000, K=256, N=64), A bf16 internal
        {
            dim3 grid((NN + 127) / 128, 1);
            gemm_gl<64, 2><<<grid, 256, 0, stream>>>(hb, nullptr, wct_hi, wct_lo,
                                                     hw2b, NN, 64, 256, flags, 2);
        }
        gather_out<<<(NN + 3) / 4, 256, 0, stream>>>(rowptr, csr, hw2b, bc, bk, bd,
                                                     dinv, flags, d_out);
    }

    e = hipGetLastError();
    if (herr == hipSuccess && e != hipSuccess) herr = e;

    if (herr != hipSuccess) {
        (void)hipMemsetAsync(d_out, 0x41 + ((int)herr & 7), 128, stream);
    }
    if (ws_bad) {
        (void)hipMemsetAsync(d_out, 0x58, 128, stream);
    }
}

// Round 5
// 1276.121 us; speedup vs baseline: 1.5968x; 1.0047x over previous
//
#include <hip/hip_runtime.h>

#define NN 100000

typedef __attribute__((ext_vector_type(8))) __bf16 bf16x8;
typedef __attribute__((ext_vector_type(8))) unsigned short ushort8v;
typedef __attribute__((ext_vector_type(4))) float f32x4;

__device__ __forceinline__ float bf2f(unsigned short u) {
    union { unsigned int ui; float f; } c;
    c.ui = ((unsigned int)u) << 16;
    return c.f;
}

__device__ __forceinline__ unsigned short f2bf(float f) {
    union { float ff; unsigned int ui; } c;
    c.ff = f;
    unsigned int u = c.ui;
    u += 0x7FFFu + ((u >> 16) & 1u);   // round-to-nearest-even
    return (unsigned short)(u >> 16);
}

// truncation split: x = hi + resid, hi = bf16-truncate(x)
__device__ __forceinline__ unsigned short trunc_hi(float x, float& resid) {
    union { float f; unsigned int u; } c, h;
    c.f = x;
    h.u = c.u & 0xFFFF0000u;
    resid = x - h.f;
    return (unsigned short)(c.u >> 16);
}

__device__ __forceinline__ unsigned short trunc_bits(float x) {
    union { float f; unsigned int u; } c;
    c.f = x;
    return (unsigned short)(c.u >> 16);
}

// async global->LDS, 16B per lane; LDS dst is wave-uniform base + lane*16 (HW).
__device__ __forceinline__ void gload_lds16(const void* g, void* l) {
    void* gnc = (void*)g;
    __builtin_amdgcn_global_load_lds((__attribute__((address_space(1))) void*)gnc,
                                     (__attribute__((address_space(3))) void*)l,
                                     16, 0, 0);
}

__global__ void MultiTaskGCN_37623913513359_kernel() {}

// flags[0]: edge index format, 1 = int64, 0 = int32
// flags[1]: float dtype, 1 = bf16-backed, 0 = fp32-backed
__global__ void probe_fmt(const int* ei, const unsigned short* x, int* flags) {
    if (blockIdx.x != 0 || threadIdx.x != 0) return;
    int any = 0;
    for (int i = 0; i < 64; ++i) any |= ei[2 * i + 1];
    flags[0] = (any == 0) ? 1 : 0;
    int bf = 1;
    for (int i = 0; i < 512; ++i) {
        float v = bf2f(x[2 * i]);
        float av = v < 0.0f ? -v : v;
        if (!(v == v) || av > 1.0e6f) { bf = 0; break; }
    }
    flags[1] = bf;
}

__device__ __forceinline__ int edge_src(const int* ei, int is64, int e) {
    if (is64) return ei[2 * e];
    return ei[e];
}
__device__ __forceinline__ int edge_dst(const int* ei, int is64, int e, int E) {
    if (is64) return ei[2 * (E + e)];
    return ei[E + e];
}

__device__ __forceinline__ float load_f(const void* p, int dt, size_t i) {
    if (dt) return bf2f(((const unsigned short*)p)[i]);
    return ((const float*)p)[i];
}

__global__ __launch_bounds__(256) void count_deg_i(const int* ei, const int* flags,
                                                   int* degi, int E) {
    int t = blockIdx.x * 256 + threadIdx.x;
    if (t >= E) return;
    int is64 = flags[0];
    int s = edge_src(ei, is64, t);
    int d = edge_dst(ei, is64, t, E);
    if (((unsigned)s) >= NN || ((unsigned)d) >= NN) return;
    atomicAdd(&degi[d], 1);
}

__global__ __launch_bounds__(256) void make_dinv(const int* degi, float* dinv) {
    int i = blockIdx.x * 256 + threadIdx.x;
    if (i < NN) dinv[i] = rsqrtf((float)degi[i] + 1.0f);   // +1 self loop
}

// single-block exclusive scan of degi -> rowptr (NN+1 entries)
__global__ __launch_bounds__(1024) void scan_rowptr(const int* degi, int* rowptr) {
    __shared__ int part[1024];
    int tid = threadIdx.x;
    const int chunk = (NN + 1023) / 1024;   // 98
    int base = tid * chunk;
    int s = 0;
    for (int j = 0; j < chunk; ++j) {
        int i = base + j;
        if (i < NN) s += degi[i];
    }
    part[tid] = s;
    __syncthreads();
    for (int off = 1; off < 1024; off <<= 1) {
        int v = (tid >= off) ? part[tid - off] : 0;
        __syncthreads();
        part[tid] += v;
        __syncthreads();
    }
    int run = (tid == 0) ? 0 : part[tid - 1];
    for (int j = 0; j < chunk; ++j) {
        int i = base + j;
        if (i < NN) {
            rowptr[i] = run;
            run += degi[i];
        }
    }
    if (tid == 1023) rowptr[NN] = part[1023];
}

// fill CSR: packed entry = (w_bits << 32) | src
__global__ __launch_bounds__(256) void fill_csr(const int* ei, const int* flags,
                                                const float* dinv, const int* rowptr,
                                                int* cursor, unsigned long long* csr,
                                                int E) {
    int t = blockIdx.x * 256 + threadIdx.x;
    if (t >= E) return;
    int is64 = flags[0];
    int s = edge_src(ei, is64, t);
    int d = edge_dst(ei, is64, t, E);
    if (((unsigned)s) >= NN || ((unsigned)d) >= NN) return;
    int pos = rowptr[d] + atomicAdd(&cursor[d], 1);
    float w = dinv[s] * dinv[d];
    union { float ff; unsigned int ui; } c;
    c.ff = w;
    csr[pos] = ((unsigned long long)c.ui << 32) | (unsigned int)s;
}

// W1 (row-major [512][256], fp32 or bf16) -> W1T hi/lo bf16 [256 n][512 k]
__global__ __launch_bounds__(256) void prep_w1t(const void* W1, const int* flags,
                                                unsigned short* hi, unsigned short* lo) {
    int t = blockIdx.x * 256 + threadIdx.x;
    if (t >= 256 * 512) return;
    int n = t >> 9, k = t & 511;
    float v = load_f(W1, flags[1], (size_t)k * 256 + n);
    float r;
    hi[t] = trunc_hi(v, r);
    lo[t] = trunc_bits(r);
}

// [Wc | Wk | Wd | 0] -> WcatT hi/lo bf16 [64 n][256 k]
__global__ __launch_bounds__(256) void prep_wcat(const void* Wc, const void* Wk,
                                                 const void* Wd, const int* flags,
                                                 unsigned short* hi, unsigned short* lo) {
    int t = blockIdx.x * 256 + threadIdx.x;
    if (t >= 64 * 256) return;
    int n = t >> 8, k = t & 255;
    int dt = flags[1];
    float v = 0.0f;
    if (n < 40) v = load_f(Wc, dt, (size_t)k * 40 + n);
    else if (n < 56) v = load_f(Wk, dt, (size_t)k * 16 + (n - 40));
    else if (n == 56) v = load_f(Wd, dt, k);
    float r;
    hi[t] = trunc_hi(v, r);
    lo[t] = trunc_bits(r);
}

// x fp32 [NN][512] -> xs: per 8-elem group, [8x hi bf16 (16B)][8x lo bf16 (16B)]
__global__ __launch_bounds__(256) void split_x(const float* x, unsigned char* xs,
                                               const int* flags, long long ngrp) {
    if (flags[1]) return;
    long long i0 = (long long)blockIdx.x * 256 + threadIdx.x;
    long long stride = (long long)gridDim.x * 256;
    for (long long g = i0; g < ngrp; g += stride) {
        const float* p = x + g * 8;
        f32x4 v0 = *(const f32x4*)p;
        f32x4 v1 = *(const f32x4*)(p + 4);
        ushort8v h, l;
        float r;
#pragma unroll
        for (int j = 0; j < 4; ++j) {
            h[j] = trunc_hi(v0[j], r);
            l[j] = trunc_bits(r);
        }
#pragma unroll
        for (int j = 0; j < 4; ++j) {
            h[4 + j] = trunc_hi(v1[j], r);
            l[4 + j] = trunc_bits(r);
        }
        *(ushort8v*)(xs + g * 32) = h;
        *(ushort8v*)(xs + g * 32 + 16) = l;
    }
}

// ---------------- MFMA GEMM: global_load_lds staging ----------------

template<int BN, int NF>
__global__ __launch_bounds__(256, 3) void gemm_gl(const void* A, const void* Axs,
                                                  const unsigned short* BTh,
                                                  const unsigned short* BTl,
                                                  unsigned short* C,
                                                  int M, int N, int K,
                                                  const int* flags, int amode) {
    constexpr int BM = 128;
    constexpr int HB = BN / 64;         // B col-halves
    __shared__ ushort8v smem[4 * BM + 4 * BM + 4 * BN + 4 * BN];
    ushort8v* Ash = smem;
    ushort8v* Asl = smem + 4 * BM;
    ushort8v* Bsh = smem + 8 * BM;
    ushort8v* Bsl = smem + 8 * BM + 4 * BN;

    const int tid = threadIdx.x;
    const int lane = tid & 63;
    const int wid = tid >> 6;
    const int wm = wid >> 1;
    const int wn = wid & 1;
    const int dt = flags[1];

    const unsigned char* Ab;
    int rowbytes, gstep, alo;
    if (amode == 0 && dt == 0) {
        Ab = (const unsigned char*)Axs; rowbytes = K * 4; gstep = 32; alo = 1;
    } else {
        Ab = (const unsigned char*)A;   rowbytes = K * 2; gstep = 16; alo = 0;
    }
    const int blo = (dt == 0) ? 1 : 0;

    const int m0 = blockIdx.x * BM;
    const int n0 = blockIdx.y * BN;

    f32x4 zero = {0.0f, 0.0f, 0.0f, 0.0f};
    f32x4 acc[4][NF];
#pragma unroll
    for (int i = 0; i < 4; ++i)
#pragma unroll
        for (int j = 0; j < NF; ++j) acc[i][j] = zero;

    const int nT = K >> 5;              // K-steps of 32
    for (int t = 0; t < nT; ++t) {
        const int k0 = t << 5;
        const int G0 = t << 2;
        for (int q = wid; q < 8; q += 4) {
            int kg = q >> 1, hf = q & 1;
            int row = m0 + hf * 64 + lane;
            if (row >= M) row = M - 1;
            const unsigned char* g = Ab + (size_t)row * rowbytes + (size_t)(G0 + kg) * gstep;
            gload_lds16(g, Ash + kg * BM + hf * 64);
            if (alo) gload_lds16(g + 16, Asl + kg * BM + hf * 64);
        }
        for (int q = wid; q < 4 * HB; q += 4) {
            int kg = q / HB, hf = q % HB;
            int col = n0 + hf * 64 + lane;
            const unsigned short* gh = BTh + (size_t)col * K + k0 + kg * 8;
            gload_lds16(gh, Bsh + kg * BN + hf * 64);
            if (blo) gload_lds16(BTl + (size_t)col * K + k0 + kg * 8, Bsl + kg * BN + hf * 64);
        }
        __syncthreads();

        {
            const int lr = lane & 15;
            const int lk = lane >> 4;
            bf16x8 ah[4], al[4];
#pragma unroll
            for (int i = 0; i < 4; ++i) {
                ah[i] = *(const bf16x8*)&Ash[lk * BM + wm * 64 + i * 16 + lr];
                if (alo) al[i] = *(const bf16x8*)&Asl[lk * BM + wm * 64 + i * 16 + lr];
            }
            bf16x8 bh[NF], bl[NF];
#pragma unroll
            for (int j = 0; j < NF; ++j) {
                bh[j] = *(const bf16x8*)&Bsh[lk * BN + wn * (NF * 16) + j * 16 + lr];
                if (blo) bl[j] = *(const bf16x8*)&Bsl[lk * BN + wn * (NF * 16) + j * 16 + lr];
            }
#pragma unroll
            for (int i = 0; i < 4; ++i) {
#pragma unroll
                for (int j = 0; j < NF; ++j) {
                    acc[i][j] = __builtin_amdgcn_mfma_f32_16x16x32_bf16(ah[i], bh[j], acc[i][j], 0, 0, 0);
                    if (blo) acc[i][j] = __builtin_amdgcn_mfma_f32_16x16x32_bf16(ah[i], bl[j], acc[i][j], 0, 0, 0);
                    if (alo) acc[i][j] = __builtin_amdgcn_mfma_f32_16x16x32_bf16(al[i], bh[j], acc[i][j], 0, 0, 0);
                }
            }
        }
        __syncthreads();
    }

    // epilogue: acc -> LDS [BM][BN] bf16 -> coalesced 16B stores
    unsigned short* cs = (unsigned short*)smem;
    const int lr = lane & 15;
    const int lq = lane >> 4;
#pragma unroll
    for (int i = 0; i < 4; ++i) {
#pragma unroll
        for (int j = 0; j < NF; ++j) {
#pragma unroll
            for (int rr = 0; rr < 4; ++rr) {
                int row = wm * 64 + i * 16 + lq * 4 + rr;
                int col = wn * (NF * 16) + j * 16 + lr;
                cs[row * BN + col] = f2bf(acc[i][j][rr]);
            }
        }
    }
    __syncthreads();
    constexpr int TOTAL = BM * BN;
#pragma unroll
    for (int base = 0; base < TOTAL; base += 2048) {
        int idx = base + tid * 8;
        int r = idx / BN;
        int c = idx % BN;
        int grow = m0 + r;
        if (grow < M) {
            *(ushort8v*)(C + (size_t)grow * N + n0 + c) = *(const ushort8v*)(cs + idx);
        }
    }
}

// ---------------- legacy reg-staged MFMA GEMM (fallback when ws too small) ----

template<int NB>
struct StageRegs {
    ushort8v ah[2], al[2], bh[NB], bl[NB];
};

template<int NB>
__device__ __forceinline__ StageRegs<NB> stage_load(const void* A, const unsigned short* BTh,
                                                    const unsigned short* BTl, int M, int K,
                                                    int m0, int n0, int k0,
                                                    int lane, int wid, int adt, bool blo) {
    StageRegs<NB> s;
#pragma unroll
    for (int half = 0; half < 2; ++half) {
        int gr = m0 + lane + half * 64;
        if (gr >= M) gr = M - 1;
        if (adt == 0) {
            const float* ap = (const float*)A + (size_t)gr * K + k0 + wid * 8;
            f32x4 v0 = *(const f32x4*)ap;
            f32x4 v1 = *(const f32x4*)(ap + 4);
            ushort8v h, l;
#pragma unroll
            for (int j = 0; j < 4; ++j) {
                float r;
                h[j] = trunc_hi(v0[j], r);
                l[j] = trunc_bits(r);
            }
#pragma unroll
            for (int j = 0; j < 4; ++j) {
                float r;
                h[4 + j] = trunc_hi(v1[j], r);
                l[4 + j] = trunc_bits(r);
            }
            s.ah[half] = h;
            s.al[half] = l;
        } else {
            s.ah[half] = *(const ushort8v*)((const unsigned short*)A + (size_t)gr * K + k0 + wid * 8);
        }
    }
#pragma unroll
    for (int nb = 0; nb < NB; ++nb) {
        size_t o = (size_t)(n0 + lane + nb * 64) * K + k0 + wid * 8;
        s.bh[nb] = *(const ushort8v*)(BTh + o);
        if (blo) s.bl[nb] = *(const ushort8v*)(BTl + o);
    }
    return s;
}

template<int BM, int BN, int NB>
__device__ __forceinline__ void stage_write(ushort8v (&As)[2][4][BM], ushort8v (&Bs)[2][4][BN],
                                            const StageRegs<NB>& s, int lane, int wid,
                                            bool alo, bool blo) {
    As[0][wid][lane] = s.ah[0];
    As[0][wid][lane + 64] = s.ah[1];
    if (alo) {
        As[1][wid][lane] = s.al[0];
        As[1][wid][lane + 64] = s.al[1];
    }
#pragma unroll
    for (int nb = 0; nb < NB; ++nb) {
        Bs[0][wid][lane + nb * 64] = s.bh[nb];
        if (blo) Bs[1][wid][lane + nb * 64] = s.bl[nb];
    }
}

template<int BM, int BN, int NF>
__device__ __forceinline__ void mfma_step(const ushort8v (&As)[2][4][BM],
                                          const ushort8v (&Bs)[2][4][BN],
                                          f32x4 (&acc)[4][NF],
                                          int wm, int wn, int lane, bool alo, bool blo) {
    const int lr = lane & 15;
    const int lk = lane >> 4;
    bf16x8 ah[4], al[4];
#pragma unroll
    for (int i = 0; i < 4; ++i) {
        ah[i] = *(const bf16x8*)&As[0][lk][wm * 64 + i * 16 + lr];
        if (alo) al[i] = *(const bf16x8*)&As[1][lk][wm * 64 + i * 16 + lr];
    }
    bf16x8 bh[NF], bl[NF];
#pragma unroll
    for (int j = 0; j < NF; ++j) {
        bh[j] = *(const bf16x8*)&Bs[0][lk][wn * (BN / 2) + j * 16 + lr];
        if (blo) bl[j] = *(const bf16x8*)&Bs[1][lk][wn * (BN / 2) + j * 16 + lr];
    }
#pragma unroll
    for (int i = 0; i < 4; ++i) {
#pragma unroll
        for (int j = 0; j < NF; ++j) {
            acc[i][j] = __builtin_amdgcn_mfma_f32_16x16x32_bf16(ah[i], bh[j], acc[i][j], 0, 0, 0);
            if (blo) acc[i][j] = __builtin_amdgcn_mfma_f32_16x16x32_bf16(ah[i], bl[j], acc[i][j], 0, 0, 0);
            if (alo) acc[i][j] = __builtin_amdgcn_mfma_f32_16x16x32_bf16(al[i], bh[j], acc[i][j], 0, 0, 0);
        }
    }
}

template<int BN, int NF>
__global__ __launch_bounds__(256) void gemm_mfma(const void* A, const unsigned short* BTh,
                                                 const unsigned short* BTl, unsigned short* C,
                                                 int M, int N, int K, const int* flags, int amode) {
    constexpr int BM = 128;
    constexpr int NB = BN / 64;
    __shared__ ushort8v As[2][4][BM];
    __shared__ ushort8v Bs[2][4][BN];

    const int tid = threadIdx.x;
    const int lane = tid & 63;
    const int wid = tid >> 6;
    const int wm = wid >> 1;
    const int wn = wid & 1;
    const int dt = flags[1];
    const int adt = (amode == 0) ? dt : 1;
    const bool alo = (adt == 0);
    const bool blo = (dt == 0);
    const int m0 = blockIdx.x * BM;
    const int n0 = blockIdx.y * BN;

    f32x4 zero = {0.0f, 0.0f, 0.0f, 0.0f};
    f32x4 acc[4][NF];
#pragma unroll
    for (int i = 0; i < 4; ++i)
#pragma unroll
        for (int j = 0; j < NF; ++j) acc[i][j] = zero;

    StageRegs<NB> sA = stage_load<NB>(A, BTh, BTl, M, K, m0, n0, 0, lane, wid, adt, blo);
    const int nT = K >> 5;
    for (int t = 0; t < nT; t += 2) {
        __syncthreads();
        stage_write<BM, BN, NB>(As, Bs, sA, lane, wid, alo, blo);
        __syncthreads();
        StageRegs<NB> sB = stage_load<NB>(A, BTh, BTl, M, K, m0, n0, (t + 1) << 5, lane, wid, adt, blo);
        mfma_step<BM, BN, NF>(As, Bs, acc, wm, wn, lane, alo, blo);
        __syncthreads();
        stage_write<BM, BN, NB>(As, Bs, sB, lane, wid, alo, blo);
        __syncthreads();
        if (t + 2 < nT)
            sA = stage_load<NB>(A, BTh, BTl, M, K, m0, n0, (t + 2) << 5, lane, wid, adt, blo);
        mfma_step<BM, BN, NF>(As, Bs, acc, wm, wn, lane, alo, blo);
    }

    const int lr = lane & 15;
    const int lq = lane >> 4;
#pragma unroll
    for (int i = 0; i < 4; ++i) {
#pragma unroll
        for (int rr = 0; rr < 4; ++rr) {
            int row = m0 + wm * 64 + i * 16 + lq * 4 + rr;
            if (row < M) {
#pragma unroll
                for (int j = 0; j < NF; ++j) {
                    int col = n0 + wn * (BN / 2) + j * 16 + lr;
                    C[(size_t)row * N + col] = f2bf(acc[i][j][rr]);
                }
            }
        }
    }
}

// layer-1 aggregation: one wave per node; lanes 0-31 = even edge, 32-63 = odd edge,
// each lane covers 8 cols (16B). 4 paired loads/iter = 8 edges in flight.
// Cross-half merge at the end via shfl_xor(32).
__global__ __launch_bounds__(256) void gather_h(const int* rowptr,
                                                const unsigned long long* csr,
                                                const unsigned short* xwb,
                                                const void* b1,
                                                const float* dinv,
                                                const int* flags,
                                                unsigned short* hb) {
    int node = (blockIdx.x * 256 + threadIdx.x) >> 6;
    int lane = threadIdx.x & 63;
    if (node >= NN) return;
    int beg = rowptr[node], end = rowptr[node + 1];
    int half = lane >> 5;
    int sub = lane & 31;
    const unsigned short* xp = xwb + (size_t)sub * 8;

    float acc[8] = {0.f, 0.f, 0.f, 0.f, 0.f, 0.f, 0.f, 0.f};

    int e = beg;
    for (; e + 8 <= end; e += 8) {
        unsigned long long p0 = csr[e + 0 + half];
        unsigned long long p1 = csr[e + 2 + half];
        unsigned long long p2 = csr[e + 4 + half];
        unsigned long long p3 = csr[e + 6 + half];
        ushort8v v0 = *(const ushort8v*)(xp + ((size_t)(unsigned int)p0) * 256);
        ushort8v v1 = *(const ushort8v*)(xp + ((size_t)(unsigned int)p1) * 256);
        ushort8v v2 = *(const ushort8v*)(xp + ((size_t)(unsigned int)p2) * 256);
        ushort8v v3 = *(const ushort8v*)(xp + ((size_t)(unsigned int)p3) * 256);
        union { unsigned int ui; float ff; } w0, w1, w2, w3;
        w0.ui = (unsigned int)(p0 >> 32);
        w1.ui = (unsigned int)(p1 >> 32);
        w2.ui = (unsigned int)(p2 >> 32);
        w3.ui = (unsigned int)(p3 >> 32);
#pragma unroll
        for (int j = 0; j < 8; ++j) acc[j] += w0.ff * bf2f(v0[j]);
#pragma unroll
        for (int j = 0; j < 8; ++j) acc[j] += w1.ff * bf2f(v1[j]);
#pragma unroll
        for (int j = 0; j < 8; ++j) acc[j] += w2.ff * bf2f(v2[j]);
#pragma unroll
        for (int j = 0; j < 8; ++j) acc[j] += w3.ff * bf2f(v3[j]);
    }
    for (; e < end; e += 2) {
        int idx = e + half;
        unsigned long long p = (idx < end) ? csr[idx] : 0ull;  // p=0 -> w=0, row 0 (safe)
        union { unsigned int ui; float ff; } w;
        w.ui = (unsigned int)(p >> 32);
        ushort8v v = *(const ushort8v*)(xp + ((size_t)(unsigned int)p) * 256);
#pragma unroll
        for (int j = 0; j < 8; ++j) acc[j] += w.ff * bf2f(v[j]);
    }

    // merge halves: lane l and l^32 hold same 8 cols over disjoint edge sets
#pragma unroll
    for (int j = 0; j < 8; ++j) acc[j] += __shfl_xor(acc[j], 32, 64);

    int dt = flags[1];
    float di = dinv[node];
    float sl = di * di;
    size_t base = (size_t)node * 256 + (size_t)sub * 8;
    ushort8v sv = *(const ushort8v*)(xwb + base);
    ushort8v o;
#pragma unroll
    for (int j = 0; j < 8; ++j) {
        float r = sl * bf2f(sv[j]) + acc[j] + load_f(b1, dt, sub * 8 + j);
        if (r < 0.f) r = 0.f;
        o[j] = f2bf(r);
    }
    if (half == 0) {
        *(ushort8v*)(hb + base) = o;
    }
}

// layer-2 aggregation: one wave per node; lane group grp=lane>>4 takes edge e+grp,
// each lane covers 4 cols (8B). 4 quad-loads/iter = 16 edges in flight.
// Reduce across groups via shfl_xor(16)+shfl_xor(32); lanes 0-15 route heads.
__global__ __launch_bounds__(256) void gather_out(const int* rowptr,
                                                  const unsigned long long* csr,
                                                  const unsigned short* hw2b,
                                                  const void* bc, const void* bk,
                                                  const void* bd,
                                                  const float* dinv,
                                                  const int* flags,
                                                  void* outv) {
    int node = (blockIdx.x * 256 + threadIdx.x) >> 6;
    int lane = threadIdx.x & 63;
    if (node >= NN) return;
    int beg = rowptr[node], end = rowptr[node + 1];
    int grp = lane >> 4;
    int sub = lane & 15;
    const unsigned short* hp = hw2b + (size_t)sub * 4;

    float acc[4] = {0.f, 0.f, 0.f, 0.f};

    int e = beg;
    for (; e + 16 <= end; e += 16) {
        unsigned long long p0 = csr[e + grp];
        unsigned long long p1 = csr[e + 4 + grp];
        unsigned long long p2 = csr[e + 8 + grp];
        unsigned long long p3 = csr[e + 12 + grp];
        unsigned long long v0 = *(const unsigned long long*)(hp + ((size_t)(unsigned int)p0) * 64);
        unsigned long long v1 = *(const unsigned long long*)(hp + ((size_t)(unsigned int)p1) * 64);
        unsigned long long v2 = *(const unsigned long long*)(hp + ((size_t)(unsigned int)p2) * 64);
        unsigned long long v3 = *(const unsigned long long*)(hp + ((size_t)(unsigned int)p3) * 64);
        union { unsigned int ui; float ff; } w0, w1, w2, w3;
        w0.ui = (unsigned int)(p0 >> 32);
        w1.ui = (unsigned int)(p1 >> 32);
        w2.ui = (unsigned int)(p2 >> 32);
        w3.ui = (unsigned int)(p3 >> 32);
#pragma unroll
        for (int j = 0; j < 4; ++j) acc[j] += w0.ff * bf2f((unsigned short)(v0 >> (16 * j)));
#pragma unroll
        for (int j = 0; j < 4; ++j) acc[j] += w1.ff * bf2f((unsigned short)(v1 >> (16 * j)));
#pragma unroll
        for (int j = 0; j < 4; ++j) acc[j] += w2.ff * bf2f((unsigned short)(v2 >> (16 * j)));
#pragma unroll
        for (int j = 0; j < 4; ++j) acc[j] += w3.ff * bf2f((unsigned short)(v3 >> (16 * j)));
    }
    for (; e < end; e += 4) {
        int idx = e + grp;
        unsigned long long p = (idx < end) ? csr[idx] : 0ull;
        union { unsigned int ui; float ff; } w;
        w.ui = (unsigned int)(p >> 32);
        unsigned long long v = *(const unsigned long long*)(hp + ((size_t)(unsigned int)p) * 64);
#pragma unroll
        for (int j = 0; j < 4; ++j) acc[j] += w.ff * bf2f((unsigned short)(v >> (16 * j)));
    }

#pragma unroll
    for (int j = 0; j < 4; ++j) {
        acc[j] += __shfl_xor(acc[j], 16, 64);
        acc[j] += __shfl_xor(acc[j], 32, 64);
    }

    if (lane >= 16) return;
    int dt = flags[1];
    float di = dinv[node];
    float sl = di * di;
#pragma unroll
    for (int j = 0; j < 4; ++j) {
        int c = sub * 4 + j;
        if (c >= 57) continue;
        float v = sl * bf2f(hw2b[(size_t)node * 64 + c]) + acc[j];
        size_t o;
        if (c < 40) {
            v += load_f(bc, dt, c);
            o = (size_t)node * 40 + c;
        } else if (c < 56) {
            v += load_f(bk, dt, c - 40);
            o = (size_t)NN * 40 + (size_t)node * 16 + (c - 40);
        } else {
            v += load_f(bd, dt, 0);
            o = (size_t)NN * 56 + node;
        }
        if (dt) ((unsigned short*)outv)[o] = f2bf(v);
        else ((float*)outv)[o] = v;
    }
}

extern "C" void kernel_launch(void* const* d_in, const int* in_sizes, int n_in,
                              void* d_out, int out_size, void* d_ws, size_t ws_size,
                              hipStream_t stream) {
    const void* x  = d_in[0];
    const int* ei  = (const int*)d_in[1];
    const void* W1 = d_in[2];
    const void* b1 = d_in[3];
    const void* Wc = d_in[4];
    const void* bc = d_in[5];
    const void* Wk = d_in[6];
    const void* bk = d_in[7];
    const void* Wd = d_in[8];
    const void* bd = d_in[9];

    int E = in_sizes[1] / 2;

    hipError_t herr = hipSuccess;
    hipError_t e;

    // workspace layout (256B-aligned offsets)
    char* ws = (char*)d_ws;
    size_t off = 0;
    int* flags = (int*)(ws + off);                      off += 256;
    float* dinv = (float*)(ws + off);                   off += 400128;
    int* rowptr = (int*)(ws + off);                     off += 400384;   // NN+1
    char* scr = ws + off;                               off += 800256;
    // scratch phase 1 (graph build): degi + cursor
    int* degi = (int*)scr;
    int* cursor = (int*)(scr + 400128);
    // scratch phase 2 (after fill_csr): split weight tables
    unsigned short* w1t_hi = (unsigned short*)scr;
    unsigned short* w1t_lo = (unsigned short*)(scr + 262144);
    unsigned short* wct_hi = (unsigned short*)(scr + 524288);
    unsigned short* wct_lo = (unsigned short*)(scr + 557056);
    unsigned long long* csr = (unsigned long long*)(ws + off); off += (size_t)E * 8;
    unsigned short* xwb = (unsigned short*)(ws + off);  off += (size_t)NN * 256 * 2;
    unsigned short* hb = (unsigned short*)(ws + off);   off += (size_t)NN * 256 * 2;
    unsigned short* hw2b = (unsigned short*)(ws + off); off += (size_t)NN * 64 * 2;

    int ws_bad = (off > ws_size) ? 1 : 0;

    // optional fast-path buffer: interleaved hi/lo bf16 split of x (204.8 MB)
    unsigned char* xs = (unsigned char*)(ws + off);
    size_t xs_bytes = (size_t)NN * 512 * 4;
    int fast = (!ws_bad && (off + xs_bytes) <= ws_size) ? 1 : 0;

    if (!ws_bad) {
        e = hipMemsetAsync(degi, 0, (size_t)NN * 4, stream);
        if (herr == hipSuccess && e != hipSuccess) herr = e;
        e = hipMemsetAsync(cursor, 0, (size_t)NN * 4, stream);
        if (herr == hipSuccess && e != hipSuccess) herr = e;

        probe_fmt<<<1, 64, 0, stream>>>(ei, (const unsigned short*)x, flags);
        count_deg_i<<<(E + 255) / 256, 256, 0, stream>>>(ei, flags, degi, E);
        make_dinv<<<(NN + 255) / 256, 256, 0, stream>>>(degi, dinv);
        scan_rowptr<<<1, 1024, 0, stream>>>(degi, rowptr);
        fill_csr<<<(E + 255) / 256, 256, 0, stream>>>(ei, flags, dinv, rowptr,
                                                      cursor, csr, E);

        // degi/cursor dead from here
        prep_w1t<<<512, 256, 0, stream>>>(W1, flags, w1t_hi, w1t_lo);
        prep_wcat<<<64, 256, 0, stream>>>(Wc, Wk, Wd, flags, wct_hi, wct_lo);

        // layer 1: xw = x @ W1   (M=100000, K=512, N=256)
        if (fast) {
            split_x<<<4096, 256, 0, stream>>>((const float*)x, xs, flags,
                                              (long long)NN * 512 / 8);
            dim3 grid((NN + 127) / 128, 2);
            gemm_gl<128, 4><<<grid, 256, 0, stream>>>(x, xs, w1t_hi, w1t_lo, xwb,
                                                      NN, 256, 512, flags, 0);
        } else {
            dim3 grid((NN + 127) / 128, 2);
            gemm_mfma<128, 4><<<grid, 256, 0, stream>>>(x, w1t_hi, w1t_lo, xwb,
                                                        NN, 256, 512, flags, 0);
        }
        gather_h<<<(NN + 3) / 4, 256, 0, stream>>>(rowptr, csr, xwb, b1, dinv,
                                                   flags, hb);

        // layer 2: hw2 = h @ Wcat   (M=100000, K=256, N=64), A bf16 internal
        {
            dim3 grid((NN + 127) / 128, 1);
            gemm_gl<64, 2><<<grid, 256, 0, stream>>>(hb, nullptr, wct_hi, wct_lo,
                                                     hw2b, NN, 64, 256, flags, 2);
        }
        gather_out<<<(NN + 3) / 4, 256, 0, stream>>>(rowptr, csr, hw2b, bc, bk, bd,
                                                     dinv, flags, d_out);
    }

    e = hipGetLastError();
    if (herr == hipSuccess && e != hipSuccess) herr = e;

    if (herr != hipSuccess) {
        (void)hipMemsetAsync(d_out, 0x41 + ((int)herr & 7), 128, stream);
    }
    if (ws_bad) {
        (void)hipMemsetAsync(d_out, 0x58, 128, stream);
    }
}

// Round 7
// 1198.992 us; speedup vs baseline: 1.6996x; 1.0643x over previous
//
#include <hip/hip_runtime.h>

#define NN 100000

typedef __attribute__((ext_vector_type(8))) __bf16 bf16x8;
typedef __attribute__((ext_vector_type(8))) unsigned short ushort8v;
typedef __attribute__((ext_vector_type(4))) float f32x4;

__device__ __forceinline__ float bf2f(unsigned short u) {
    union { unsigned int ui; float f; } c;
    c.ui = ((unsigned int)u) << 16;
    return c.f;
}

__device__ __forceinline__ unsigned short f2bf(float f) {
    union { float ff; unsigned int ui; } c;
    c.ff = f;
    unsigned int u = c.ui;
    u += 0x7FFFu + ((u >> 16) & 1u);   // round-to-nearest-even
    return (unsigned short)(u >> 16);
}

// truncation split: x = hi + resid, hi = bf16-truncate(x)
__device__ __forceinline__ unsigned short trunc_hi(float x, float& resid) {
    union { float f; unsigned int u; } c, h;
    c.f = x;
    h.u = c.u & 0xFFFF0000u;
    resid = x - h.f;
    return (unsigned short)(c.u >> 16);
}

__device__ __forceinline__ unsigned short trunc_bits(float x) {
    union { float f; unsigned int u; } c;
    c.f = x;
    return (unsigned short)(c.u >> 16);
}

// async global->LDS, 16B per lane; LDS dst is wave-uniform base + lane*16 (HW).
__device__ __forceinline__ void gload_lds16(const void* g, void* l) {
    void* gnc = (void*)g;
    __builtin_amdgcn_global_load_lds((__attribute__((address_space(1))) void*)gnc,
                                     (__attribute__((address_space(3))) void*)l,
                                     16, 0, 0);
}

__global__ void MultiTaskGCN_37623913513359_kernel() {}

// flags[0]: edge index format, 1 = int64, 0 = int32
// flags[1]: float dtype, 1 = bf16-backed, 0 = fp32-backed
// wave-parallel: 64 lanes, 8 rounds of parallel loads + ballot (was 1-thread serial)
__global__ void probe_fmt(const int* ei, const unsigned short* x, int* flags) {
    if (blockIdx.x != 0 || threadIdx.x >= 64) return;
    int lane = threadIdx.x & 63;
    int any = ei[2 * lane + 1];
    unsigned long long b64 = __ballot(any != 0);
    int bad = 0;
#pragma unroll
    for (int r = 0; r < 8; ++r) {
        int i = r * 64 + lane;      // i < 512
        float v = bf2f(x[2 * i]);
        float av = v < 0.0f ? -v : v;
        if (!(v == v) || av > 1.0e6f) bad = 1;
    }
    unsigned long long bb = __ballot(bad != 0);
    if (lane == 0) {
        flags[0] = (b64 == 0) ? 1 : 0;
        flags[1] = (bb == 0) ? 1 : 0;
    }
}

__device__ __forceinline__ int edge_src(const int* ei, int is64, int e) {
    if (is64) return ei[2 * e];
    return ei[e];
}
__device__ __forceinline__ int edge_dst(const int* ei, int is64, int e, int E) {
    if (is64) return ei[2 * (E + e)];
    return ei[E + e];
}

__device__ __forceinline__ float load_f(const void* p, int dt, size_t i) {
    if (dt) return bf2f(((const unsigned short*)p)[i]);
    return ((const float*)p)[i];
}

__global__ __launch_bounds__(256) void count_deg_i(const int* ei, const int* flags,
                                                   int* degi, int E) {
    int t = blockIdx.x * 256 + threadIdx.x;
    if (t >= E) return;
    int is64 = flags[0];
    int s = edge_src(ei, is64, t);
    int d = edge_dst(ei, is64, t, E);
    if (((unsigned)s) >= NN || ((unsigned)d) >= NN) return;
    atomicAdd(&degi[d], 1);
}

__global__ __launch_bounds__(256) void make_dinv(const int* degi, float* dinv) {
    int i = blockIdx.x * 256 + threadIdx.x;
    if (i < NN) dinv[i] = rsqrtf((float)degi[i] + 1.0f);   // +1 self loop
}

// single-block exclusive scan of degi -> rowptr (NN+1 entries)
__global__ __launch_bounds__(1024) void scan_rowptr(const int* degi, int* rowptr) {
    __shared__ int part[1024];
    int tid = threadIdx.x;
    const int chunk = (NN + 1023) / 1024;   // 98
    int base = tid * chunk;
    int s = 0;
    for (int j = 0; j < chunk; ++j) {
        int i = base + j;
        if (i < NN) s += degi[i];
    }
    part[tid] = s;
    __syncthreads();
    for (int off = 1; off < 1024; off <<= 1) {
        int v = (tid >= off) ? part[tid - off] : 0;
        __syncthreads();
        part[tid] += v;
        __syncthreads();
    }
    int run = (tid == 0) ? 0 : part[tid - 1];
    for (int j = 0; j < chunk; ++j) {
        int i = base + j;
        if (i < NN) {
            rowptr[i] = run;
            run += degi[i];
        }
    }
    if (tid == 1023) rowptr[NN] = part[1023];
}

// fill CSR: packed entry = (w_bits << 32) | src
__global__ __launch_bounds__(256) void fill_csr(const int* ei, const int* flags,
                                                const float* dinv, const int* rowptr,
                                                int* cursor, unsigned long long* csr,
                                                int E) {
    int t = blockIdx.x * 256 + threadIdx.x;
    if (t >= E) return;
    int is64 = flags[0];
    int s = edge_src(ei, is64, t);
    int d = edge_dst(ei, is64, t, E);
    if (((unsigned)s) >= NN || ((unsigned)d) >= NN) return;
    int pos = rowptr[d] + atomicAdd(&cursor[d], 1);
    float w = dinv[s] * dinv[d];
    union { float ff; unsigned int ui; } c;
    c.ff = w;
    csr[pos] = ((unsigned long long)c.ui << 32) | (unsigned int)s;
}

// W1 (row-major [512][256], fp32 or bf16) -> W1T hi/lo bf16 [256 n][512 k]
__global__ __launch_bounds__(256) void prep_w1t(const void* W1, const int* flags,
                                                unsigned short* hi, unsigned short* lo) {
    int t = blockIdx.x * 256 + threadIdx.x;
    if (t >= 256 * 512) return;
    int n = t >> 9, k = t & 511;
    float v = load_f(W1, flags[1], (size_t)k * 256 + n);
    float r;
    hi[t] = trunc_hi(v, r);
    lo[t] = trunc_bits(r);
}

// [Wc | Wk | Wd | 0] -> WcatT hi/lo bf16 [64 n][256 k]
__global__ __launch_bounds__(256) void prep_wcat(const void* Wc, const void* Wk,
                                                 const void* Wd, const int* flags,
                                                 unsigned short* hi, unsigned short* lo) {
    int t = blockIdx.x * 256 + threadIdx.x;
    if (t >= 64 * 256) return;
    int n = t >> 8, k = t & 255;
    int dt = flags[1];
    float v = 0.0f;
    if (n < 40) v = load_f(Wc, dt, (size_t)k * 40 + n);
    else if (n < 56) v = load_f(Wk, dt, (size_t)k * 16 + (n - 40));
    else if (n == 56) v = load_f(Wd, dt, k);
    float r;
    hi[t] = trunc_hi(v, r);
    lo[t] = trunc_bits(r);
}

// ---------------- MFMA GEMM: global_load_lds B + in-kernel-split A ----------------
// C[M,N](bf16) = A[M,K] @ B[K,N]; B pre-transposed+split BT_hi/BT_lo [N][K] bf16.
// A modes:
//   amode=0, dt=0: A fp32 row-major -> reg-load, hi/lo split, ds_write (3-product GEMM)
//   amode=0, dt=1: A bf16 row-major -> global_load_lds, hi only
//   amode=2:       A bf16 internal buffer -> global_load_lds, hi only
// LDS k-group-major panel[kg][row]: conflict-free ds_read_b128 + linear staging.

template<int BN, int NF>
__global__ __launch_bounds__(256, 3) void gemm_gl(const void* A,
                                                  const unsigned short* BTh,
                                                  const unsigned short* BTl,
                                                  unsigned short* C,
                                                  int M, int N, int K,
                                                  const int* flags, int amode) {
    constexpr int BM = 128;
    constexpr int HB = BN / 64;         // B col-halves
    __shared__ ushort8v smem[4 * BM + 4 * BM + 4 * BN + 4 * BN];
    ushort8v* Ash = smem;
    ushort8v* Asl = smem + 4 * BM;
    ushort8v* Bsh = smem + 8 * BM;
    ushort8v* Bsl = smem + 8 * BM + 4 * BN;

    const int tid = threadIdx.x;
    const int lane = tid & 63;
    const int wid = tid >> 6;
    const int wm = wid >> 1;
    const int wn = wid & 1;
    const int dt = flags[1];

    const int alo = (amode == 0 && dt == 0) ? 1 : 0;   // fp32 A: split path
    const int blo = (dt == 0) ? 1 : 0;

    const int m0 = blockIdx.x * BM;
    const int n0 = blockIdx.y * BN;

    f32x4 zero = {0.0f, 0.0f, 0.0f, 0.0f};
    f32x4 acc[4][NF];
#pragma unroll
    for (int i = 0; i < 4; ++i)
#pragma unroll
        for (int j = 0; j < NF; ++j) acc[i][j] = zero;

    const float* Af = (const float*)A;
    const unsigned short* Ab16 = (const unsigned short*)A;

    const int nT = K >> 5;              // K-steps of 32
    for (int t = 0; t < nT; ++t) {
        const int k0 = t << 5;
        // stage B via global_load_lds (4*HB slots over 4 waves)
        for (int q = wid; q < 4 * HB; q += 4) {
            int kg = q / HB, hf = q % HB;
            int col = n0 + hf * 64 + lane;
            gload_lds16(BTh + (size_t)col * K + k0 + kg * 8, Bsh + kg * BN + hf * 64);
            if (blo) gload_lds16(BTl + (size_t)col * K + k0 + kg * 8, Bsl + kg * BN + hf * 64);
        }
        // stage A
        if (alo) {
            // fp32: reg-load both subtiles, split, ds_write
            f32x4 ra[2][2];
#pragma unroll
            for (int u = 0; u < 2; ++u) {
                int q = wid + u * 4;
                int kg = q >> 1, hf = q & 1;
                int row = m0 + hf * 64 + lane;
                if (row >= M) row = M - 1;
                const float* ap = Af + (size_t)row * K + k0 + kg * 8;
                ra[u][0] = *(const f32x4*)ap;
                ra[u][1] = *(const f32x4*)(ap + 4);
            }
#pragma unroll
            for (int u = 0; u < 2; ++u) {
                int q = wid + u * 4;
                int kg = q >> 1, hf = q & 1;
                ushort8v h, l;
                float r;
#pragma unroll
                for (int j = 0; j < 4; ++j) {
                    h[j] = trunc_hi(ra[u][0][j], r);
                    l[j] = trunc_bits(r);
                }
#pragma unroll
                for (int j = 0; j < 4; ++j) {
                    h[4 + j] = trunc_hi(ra[u][1][j], r);
                    l[4 + j] = trunc_bits(r);
                }
                Ash[kg * BM + hf * 64 + lane] = h;
                Asl[kg * BM + hf * 64 + lane] = l;
            }
        } else {
            // bf16: direct global_load_lds
            for (int q = wid; q < 8; q += 4) {
                int kg = q >> 1, hf = q & 1;
                int row = m0 + hf * 64 + lane;
                if (row >= M) row = M - 1;
                gload_lds16(Ab16 + (size_t)row * K + k0 + kg * 8, Ash + kg * BM + hf * 64);
            }
        }
        __syncthreads();   // drains vmcnt (lds-DMA) + lgkmcnt (ds_write)

        {
            const int lr = lane & 15;
            const int lk = lane >> 4;
            bf16x8 ah[4], al[4];
#pragma unroll
            for (int i = 0; i < 4; ++i) {
                ah[i] = *(const bf16x8*)&Ash[lk * BM + wm * 64 + i * 16 + lr];
                if (alo) al[i] = *(const bf16x8*)&Asl[lk * BM + wm * 64 + i * 16 + lr];
            }
            bf16x8 bh[NF], bl[NF];
#pragma unroll
            for (int j = 0; j < NF; ++j) {
                bh[j] = *(const bf16x8*)&Bsh[lk * BN + wn * (NF * 16) + j * 16 + lr];
                if (blo) bl[j] = *(const bf16x8*)&Bsl[lk * BN + wn * (NF * 16) + j * 16 + lr];
            }
#pragma unroll
            for (int i = 0; i < 4; ++i) {
#pragma unroll
                for (int j = 0; j < NF; ++j) {
                    acc[i][j] = __builtin_amdgcn_mfma_f32_16x16x32_bf16(ah[i], bh[j], acc[i][j], 0, 0, 0);
                    if (blo) acc[i][j] = __builtin_amdgcn_mfma_f32_16x16x32_bf16(ah[i], bl[j], acc[i][j], 0, 0, 0);
                    if (alo) acc[i][j] = __builtin_amdgcn_mfma_f32_16x16x32_bf16(al[i], bh[j], acc[i][j], 0, 0, 0);
                }
            }
        }
        __syncthreads();
    }

    // epilogue: acc -> LDS [BM][BN] bf16 -> coalesced 16B stores
    unsigned short* cs = (unsigned short*)smem;
    const int lr = lane & 15;
    const int lq = lane >> 4;
#pragma unroll
    for (int i = 0; i < 4; ++i) {
#pragma unroll
        for (int j = 0; j < NF; ++j) {
#pragma unroll
            for (int rr = 0; rr < 4; ++rr) {
                int row = wm * 64 + i * 16 + lq * 4 + rr;
                int col = wn * (NF * 16) + j * 16 + lr;
                cs[row * BN + col] = f2bf(acc[i][j][rr]);
            }
        }
    }
    __syncthreads();
    constexpr int TOTAL = BM * BN;
#pragma unroll
    for (int base = 0; base < TOTAL; base += 2048) {
        int idx = base + tid * 8;
        int r = idx / BN;
        int c = idx % BN;
        int grow = m0 + r;
        if (grow < M) {
            *(ushort8v*)(C + (size_t)grow * N + n0 + c) = *(const ushort8v*)(cs + idx);
        }
    }
}

// layer-1 aggregation by pull + fused epilogue: one wave per destination node.
// 4-deep unrolled edge loop (round-4 best variant: 227us, ~3.7 TB/s pattern ceiling).
__global__ __launch_bounds__(256) void gather_h(const int* rowptr,
                                                const unsigned long long* csr,
                                                const unsigned short* xwb,
                                                const void* b1,
                                                const float* dinv,
                                                const int* flags,
                                                unsigned short* hb) {
    int node = (blockIdx.x * 256 + threadIdx.x) >> 6;
    int lane = threadIdx.x & 63;
    if (node >= NN) return;
    int beg = rowptr[node], end = rowptr[node + 1];
    const unsigned short* xp = xwb + (size_t)lane * 4;

    float a0[4] = {0.f, 0.f, 0.f, 0.f};
    float a1[4] = {0.f, 0.f, 0.f, 0.f};
    float a2[4] = {0.f, 0.f, 0.f, 0.f};
    float a3[4] = {0.f, 0.f, 0.f, 0.f};

    int e = beg;
    for (; e + 4 <= end; e += 4) {
        unsigned long long p0 = csr[e + 0];
        unsigned long long p1 = csr[e + 1];
        unsigned long long p2 = csr[e + 2];
        unsigned long long p3 = csr[e + 3];
        unsigned long long v0 = *(const unsigned long long*)(xp + ((size_t)(unsigned int)p0) * 256);
        unsigned long long v1 = *(const unsigned long long*)(xp + ((size_t)(unsigned int)p1) * 256);
        unsigned long long v2 = *(const unsigned long long*)(xp + ((size_t)(unsigned int)p2) * 256);
        unsigned long long v3 = *(const unsigned long long*)(xp + ((size_t)(unsigned int)p3) * 256);
        union { unsigned int ui; float ff; } w0, w1, w2, w3;
        w0.ui = (unsigned int)(p0 >> 32);
        w1.ui = (unsigned int)(p1 >> 32);
        w2.ui = (unsigned int)(p2 >> 32);
        w3.ui = (unsigned int)(p3 >> 32);
        a0[0] += w0.ff * bf2f((unsigned short)v0);
        a0[1] += w0.ff * bf2f((unsigned short)(v0 >> 16));
        a0[2] += w0.ff * bf2f((unsigned short)(v0 >> 32));
        a0[3] += w0.ff * bf2f((unsigned short)(v0 >> 48));
        a1[0] += w1.ff * bf2f((unsigned short)v1);
        a1[1] += w1.ff * bf2f((unsigned short)(v1 >> 16));
        a1[2] += w1.ff * bf2f((unsigned short)(v1 >> 32));
        a1[3] += w1.ff * bf2f((unsigned short)(v1 >> 48));
        a2[0] += w2.ff * bf2f((unsigned short)v2);
        a2[1] += w2.ff * bf2f((unsigned short)(v2 >> 16));
        a2[2] += w2.ff * bf2f((unsigned short)(v2 >> 32));
        a2[3] += w2.ff * bf2f((unsigned short)(v2 >> 48));
        a3[0] += w3.ff * bf2f((unsigned short)v3);
        a3[1] += w3.ff * bf2f((unsigned short)(v3 >> 16));
        a3[2] += w3.ff * bf2f((unsigned short)(v3 >> 32));
        a3[3] += w3.ff * bf2f((unsigned short)(v3 >> 48));
    }
    for (; e < end; ++e) {
        unsigned long long p = csr[e];
        union { unsigned int ui; float ff; } c;
        c.ui = (unsigned int)(p >> 32);
        unsigned long long v = *(const unsigned long long*)(xp + ((size_t)(unsigned int)p) * 256);
        a0[0] += c.ff * bf2f((unsigned short)v);
        a0[1] += c.ff * bf2f((unsigned short)(v >> 16));
        a0[2] += c.ff * bf2f((unsigned short)(v >> 32));
        a0[3] += c.ff * bf2f((unsigned short)(v >> 48));
    }

    int dt = flags[1];
    float di = dinv[node];
    float sl = di * di;
    size_t base = (size_t)node * 256 + lane * 4;
    unsigned long long v = *(const unsigned long long*)(xwb + base);
    float r0 = sl * bf2f((unsigned short)v)         + (a0[0] + a1[0]) + (a2[0] + a3[0]) + load_f(b1, dt, lane * 4 + 0);
    float r1 = sl * bf2f((unsigned short)(v >> 16)) + (a0[1] + a1[1]) + (a2[1] + a3[1]) + load_f(b1, dt, lane * 4 + 1);
    float r2 = sl * bf2f((unsigned short)(v >> 32)) + (a0[2] + a1[2]) + (a2[2] + a3[2]) + load_f(b1, dt, lane * 4 + 2);
    float r3 = sl * bf2f((unsigned short)(v >> 48)) + (a0[3] + a1[3]) + (a2[3] + a3[3]) + load_f(b1, dt, lane * 4 + 3);
    if (r0 < 0.f) r0 = 0.f;
    if (r1 < 0.f) r1 = 0.f;
    if (r2 < 0.f) r2 = 0.f;
    if (r3 < 0.f) r3 = 0.f;
    unsigned long long o = (unsigned long long)f2bf(r0)
                         | ((unsigned long long)f2bf(r1) << 16)
                         | ((unsigned long long)f2bf(r2) << 32)
                         | ((unsigned long long)f2bf(r3) << 48);
    *(unsigned long long*)(hb + base) = o;
}

// layer-2 aggregation: one wave per node; lane group grp=lane>>4 takes edge e+grp,
// each lane covers 4 cols (8B). 4 quad-loads/iter = 16 edges in flight.
__global__ __launch_bounds__(256) void gather_out(const int* rowptr,
                                                  const unsigned long long* csr,
                                                  const unsigned short* hw2b,
                                                  const void* bc, const void* bk,
                                                  const void* bd,
                                                  const float* dinv,
                                                  const int* flags,
                                                  void* outv) {
    int node = (blockIdx.x * 256 + threadIdx.x) >> 6;
    int lane = threadIdx.x & 63;
    if (node >= NN) return;
    int beg = rowptr[node], end = rowptr[node + 1];
    int grp = lane >> 4;
    int sub = lane & 15;
    const unsigned short* hp = hw2b + (size_t)sub * 4;

    float acc[4] = {0.f, 0.f, 0.f, 0.f};

    int e = beg;
    for (; e + 16 <= end; e += 16) {
        unsigned long long p0 = csr[e + grp];
        unsigned long long p1 = csr[e + 4 + grp];
        unsigned long long p2 = csr[e + 8 + grp];
        unsigned long long p3 = csr[e + 12 + grp];
        unsigned long long v0 = *(const unsigned long long*)(hp + ((size_t)(unsigned int)p0) * 64);
        unsigned long long v1 = *(const unsigned long long*)(hp + ((size_t)(unsigned int)p1) * 64);
        unsigned long long v2 = *(const unsigned long long*)(hp + ((size_t)(unsigned int)p2) * 64);
        unsigned long long v3 = *(const unsigned long long*)(hp + ((size_t)(unsigned int)p3) * 64);
        union { unsigned int ui; float ff; } w0, w1, w2, w3;
        w0.ui = (unsigned int)(p0 >> 32);
        w1.ui = (unsigned int)(p1 >> 32);
        w2.ui = (unsigned int)(p2 >> 32);
        w3.ui = (unsigned int)(p3 >> 32);
#pragma unroll
        for (int j = 0; j < 4; ++j) acc[j] += w0.ff * bf2f((unsigned short)(v0 >> (16 * j)));
#pragma unroll
        for (int j = 0; j < 4; ++j) acc[j] += w1.ff * bf2f((unsigned short)(v1 >> (16 * j)));
#pragma unroll
        for (int j = 0; j < 4; ++j) acc[j] += w2.ff * bf2f((unsigned short)(v2 >> (16 * j)));
#pragma unroll
        for (int j = 0; j < 4; ++j) acc[j] += w3.ff * bf2f((unsigned short)(v3 >> (16 * j)));
    }
    for (; e < end; e += 4) {
        int idx = e + grp;
        unsigned long long p = (idx < end) ? csr[idx] : 0ull;
        union { unsigned int ui; float ff; } w;
        w.ui = (unsigned int)(p >> 32);
        unsigned long long v = *(const unsigned long long*)(hp + ((size_t)(unsigned int)p) * 64);
#pragma unroll
        for (int j = 0; j < 4; ++j) acc[j] += w.ff * bf2f((unsigned short)(v >> (16 * j)));
    }

#pragma unroll
    for (int j = 0; j < 4; ++j) {
        acc[j] += __shfl_xor(acc[j], 16, 64);
        acc[j] += __shfl_xor(acc[j], 32, 64);
    }

    if (lane >= 16) return;
    int dt = flags[1];
    float di = dinv[node];
    float sl = di * di;
#pragma unroll
    for (int j = 0; j < 4; ++j) {
        int c = sub * 4 + j;
        if (c >= 57) continue;
        float v = sl * bf2f(hw2b[(size_t)node * 64 + c]) + acc[j];
        size_t o;
        if (c < 40) {
            v += load_f(bc, dt, c);
            o = (size_t)node * 40 + c;
        } else if (c < 56) {
            v += load_f(bk, dt, c - 40);
            o = (size_t)NN * 40 + (size_t)node * 16 + (c - 40);
        } else {
            v += load_f(bd, dt, 0);
            o = (size_t)NN * 56 + node;
        }
        if (dt) ((unsigned short*)outv)[o] = f2bf(v);
        else ((float*)outv)[o] = v;
    }
}

extern "C" void kernel_launch(void* const* d_in, const int* in_sizes, int n_in,
                              void* d_out, int out_size, void* d_ws, size_t ws_size,
                              hipStream_t stream) {
    const void* x  = d_in[0];
    const int* ei  = (const int*)d_in[1];
    const void* W1 = d_in[2];
    const void* b1 = d_in[3];
    const void* Wc = d_in[4];
    const void* bc = d_in[5];
    const void* Wk = d_in[6];
    const void* bk = d_in[7];
    const void* Wd = d_in[8];
    const void* bd = d_in[9];

    int E = in_sizes[1] / 2;

    hipError_t herr = hipSuccess;
    hipError_t e;

    // workspace layout (256B-aligned offsets)
    char* ws = (char*)d_ws;
    size_t off = 0;
    int* flags = (int*)(ws + off);                      off += 256;
    float* dinv = (float*)(ws + off);                   off += 400128;
    int* rowptr = (int*)(ws + off);                     off += 400384;   // NN+1
    char* scr = ws + off;                               off += 800256;
    // scratch phase 1 (graph build): degi + cursor
    int* degi = (int*)scr;
    int* cursor = (int*)(scr + 400128);
    // scratch phase 2 (after fill_csr): split weight tables
    unsigned short* w1t_hi = (unsigned short*)scr;
    unsigned short* w1t_lo = (unsigned short*)(scr + 262144);
    unsigned short* wct_hi = (unsigned short*)(scr + 524288);
    unsigned short* wct_lo = (unsigned short*)(scr + 557056);
    unsigned long long* csr = (unsigned long long*)(ws + off); off += (size_t)E * 8;
    unsigned short* xwb = (unsigned short*)(ws + off);  off += (size_t)NN * 256 * 2;
    unsigned short* hb = (unsigned short*)(ws + off);   off += (size_t)NN * 256 * 2;
    unsigned short* hw2b = (unsigned short*)(ws + off); off += (size_t)NN * 64 * 2;

    int ws_bad = (off > ws_size) ? 1 : 0;

    if (!ws_bad) {
        e = hipMemsetAsync(degi, 0, (size_t)NN * 4, stream);
        if (herr == hipSuccess && e != hipSuccess) herr = e;
        e = hipMemsetAsync(cursor, 0, (size_t)NN * 4, stream);
        if (herr == hipSuccess && e != hipSuccess) herr = e;

        probe_fmt<<<1, 64, 0, stream>>>(ei, (const unsigned short*)x, flags);
        count_deg_i<<<(E + 255) / 256, 256, 0, stream>>>(ei, flags, degi, E);
        make_dinv<<<(NN + 255) / 256, 256, 0, stream>>>(degi, dinv);
        scan_rowptr<<<1, 1024, 0, stream>>>(degi, rowptr);
        fill_csr<<<(E + 255) / 256, 256, 0, stream>>>(ei, flags, dinv, rowptr,
                                                      cursor, csr, E);

        // degi/cursor dead from here
        prep_w1t<<<512, 256, 0, stream>>>(W1, flags, w1t_hi, w1t_lo);
        prep_wcat<<<64, 256, 0, stream>>>(Wc, Wk, Wd, flags, wct_hi, wct_lo);

        // layer 1: xw = x @ W1   (M=100000, K=512, N=256), in-kernel A split
        {
            dim3 grid((NN + 127) / 128, 2);
            gemm_gl<128, 4><<<grid, 256, 0, stream>>>(x, w1t_hi, w1t_lo, xwb,
                                                      NN, 256, 512, flags, 0);
        }
        gather_h<<<(NN + 3) / 4, 256, 0, stream>>>(rowptr, csr, xwb, b1, dinv,
                                                   flags, hb);

        // layer 2: hw2 = h @ Wcat   (M=100000, K=256, N=64), A bf16 internal
        {
            dim3 grid((NN + 127) / 128, 1);
            gemm_gl<64, 2><<<grid, 256, 0, stream>>>(hb, wct_hi, wct_lo,
                                                     hw2b, NN, 64, 256, flags, 2);
        }
        gather_out<<<(NN + 3) / 4, 256, 0, stream>>>(rowptr, csr, hw2b, bc, bk, bd,
                                                     dinv, flags, d_out);
    }

    e = hipGetLastError();
    if (herr == hipSuccess && e != hipSuccess) herr = e;

    if (herr != hipSuccess) {
        (void)hipMemsetAsync(d_out, 0x41 + ((int)herr & 7), 128, stream);
    }
    if (ws_bad) {
        (void)hipMemsetAsync(d_out, 0x58, 128, stream);
    }
}